// Round 15
// baseline (144.681 us; speedup 1.0000x reference)
//
#include <hip/hip_runtime.h>
#include <hip/hip_bf16.h>

#define NN 2048
#define DD 512
#define NBATCH 4
#define KNB 10
#define NPAIR 45

typedef __attribute__((ext_vector_type(8))) _Float16 f16x8;
typedef __attribute__((ext_vector_type(4))) float f32x4;

// ---------------------------------------------------------------------------
// helpers
// ---------------------------------------------------------------------------
__device__ __forceinline__ float tri_area(float p0x, float p0y, float p0z,
                                          float p1x, float p1y, float p1z,
                                          float p2x, float p2y, float p2z) {
    float e1x = __fsub_rn(p1x, p0x), e1y = __fsub_rn(p1y, p0y), e1z = __fsub_rn(p1z, p0z);
    float e2x = __fsub_rn(p2x, p0x), e2y = __fsub_rn(p2y, p0y), e2z = __fsub_rn(p2z, p0z);
    float c0 = __fsub_rn(__fmul_rn(e1y, e2z), __fmul_rn(e1z, e2y));
    float c1 = __fsub_rn(__fmul_rn(e1z, e2x), __fmul_rn(e1x, e2z));
    float c2 = __fsub_rn(__fmul_rn(e1x, e2y), __fmul_rn(e1y, e2x));
    float ss = __fadd_rn(__fadd_rn(__fmul_rn(c0, c0), __fmul_rn(c1, c1)), __fmul_rn(c2, c2));
    return __fmul_rn(0.5f, sqrtf(ss));
}

__device__ __forceinline__ double wave_red_sum_d(double v) {
#pragma unroll
    for (int st = 1; st < 64; st <<= 1) v += __shfl_xor(v, st, 64);
    return v;
}

// ---------------------------------------------------------------------------
// K0: prep_planes — f32 -> fp16 h plane, pre-tiled + pre-swizzled.
// Coalesced lane map: n = ng*64 + (t&63), gg = t>>6 (256B segments).
// Also zeroes `count`.
// ---------------------------------------------------------------------------
__global__ __launch_bounds__(256) void prep_planes(const float* __restrict__ srcE,
                                                   const float* __restrict__ tgtE,
                                                   short* __restrict__ Ah,
                                                   short* __restrict__ Bh,
                                                   int* __restrict__ count) {
    int kt = blockIdx.x & 15, ng = blockIdx.x >> 4;
    int b = blockIdx.y, mat = blockIdx.z;
    int t = threadIdx.x;
    if (blockIdx.x == 0 && b == 0 && mat == 0 && t == 0) count[0] = 0;
    int nloc = t & 63, gg = t >> 6;
    int n = ng * 64 + nloc;
    int d0 = kt * 32 + gg * 8;
    const float* src = (mat ? tgtE : srcE) + (size_t)b * DD * NN;
    short* PH = mat ? Bh : Ah;

    float x[8];
#pragma unroll
    for (int j = 0; j < 8; j++) x[j] = src[(size_t)(d0 + j) * NN + n];
    unsigned h4[4];
#pragma unroll
    for (int p = 0; p < 4; p++) {
        _Float16 h0 = (_Float16)x[2 * p], h1 = (_Float16)x[2 * p + 1];  // RNE
        h4[p] = (unsigned)__builtin_bit_cast(unsigned short, h0) |
                ((unsigned)__builtin_bit_cast(unsigned short, h1) << 16);
    }
    size_t o = ((size_t)(b * 16 + kt) * NN + n) * 32 + ((gg ^ ((n >> 1) & 3)) << 3);
    *(uint4*)&PH[o] = (uint4){h4[0], h4[1], h4[2], h4[3]};
}

// ---------------------------------------------------------------------------
// K1: 2-phase double-buffered MFMA GEMM (fp16 1-product) + top-2/argmax
// epilogue.  (verified; at the 2-barrier structure floor)
// ---------------------------------------------------------------------------
__global__ __launch_bounds__(256) void gemm_fused(const short* __restrict__ Ah,
                                                  const short* __restrict__ Bh,
                                                  float* __restrict__ part) {
    int b = blockIdx.z;
    int id = blockIdx.y * 16 + blockIdx.x;
    int swz = (id & 7) * 32 + (id >> 3);  // XCD-bijective (256 % 8 == 0)
    int bx = swz & 15, by = swz >> 4;
    int n0 = by * 128, m0 = bx * 128;

    __shared__ short LDS[2][2][4096];  // [buf][plane: Ah Bh] = 32 KB

    int t = threadIdx.x, w = t >> 6, lane = t & 63;
    int wr = w >> 1, wc = w & 1;
    int fr = lane & 15, kq = lane >> 4;

    const short* gpl[2] = {Ah, Bh};

    f32x4 acc[4][4];
#pragma unroll
    for (int i = 0; i < 4; i++)
#pragma unroll
        for (int j = 0; j < 4; j++) acc[i][j] = (f32x4){0.f, 0.f, 0.f, 0.f};

    auto STAGE = [&](int buf, int kt) {
#pragma unroll
        for (int q = 0; q < 4; q++) {
            int p = q >> 1, h = q & 1;
            int rb = (p == 0) ? n0 : m0;
            const short* g = gpl[p] + ((size_t)(b * 16 + kt) * NN + rb) * 32 +
                             h * 2048 + w * 512 + lane * 8;
            __builtin_amdgcn_global_load_lds(
                (const __attribute__((address_space(1))) void*)g,
                (__attribute__((address_space(3))) void*)&LDS[buf][p][h * 2048 + w * 512],
                16, 0, 0);
        }
    };

    STAGE(0, 0);
    __syncthreads();
    int cur = 0;
    for (int kt = 0; kt < 16; kt++) {
        if (kt < 15) STAGE(cur ^ 1, kt + 1);  // next tile in flight over compute

        f16x8 ah[4], bh[4];
#pragma unroll
        for (int i = 0; i < 4; i++) {
            int rA = wr * 64 + i * 16 + fr;
            int offA = rA * 32 + ((kq ^ ((rA >> 1) & 3)) << 3);
            ah[i] = *(const f16x8*)&LDS[cur][0][offA];
            int rB = wc * 64 + i * 16 + fr;
            int offB = rB * 32 + ((kq ^ ((rB >> 1) & 3)) << 3);
            bh[i] = *(const f16x8*)&LDS[cur][1][offB];
        }
#pragma unroll
        for (int i = 0; i < 4; i++)
#pragma unroll
            for (int j = 0; j < 4; j++)
                acc[i][j] = __builtin_amdgcn_mfma_f32_16x16x32_f16(ah[i], bh[j],
                                                                   acc[i][j], 0, 0, 0);
        __syncthreads();
        cur ^= 1;
    }

    // ---- top-2/argmax epilogue ----
    int t32 = bx * 2 + wc;
#pragma unroll
    for (int i = 0; i < 4; i++) {
#pragma unroll
        for (int rg = 0; rg < 4; rg++) {
            int row = n0 + wr * 64 + i * 16 + kq * 4 + rg;
            float m1 = -3.4e38f, m2 = -3.4e38f;
            int i1 = 0x7fffffff;
#pragma unroll
            for (int j = 0; j < 4; j++) {
                float vv = __fmul_rn(10000.0f, __fdiv_rn(acc[i][j][rg], 22.627416997969522f));
                int col = m0 + wc * 64 + j * 16 + fr;
                if (vv > m1) { m2 = m1; m1 = vv; i1 = col; }
                else if (vv > m2) m2 = vv;
            }
#pragma unroll
            for (int st = 1; st < 16; st <<= 1) {
                float om1 = __shfl_xor(m1, st, 64);
                float om2 = __shfl_xor(m2, st, 64);
                int oi1 = __shfl_xor(i1, st, 64);
                if (om1 > m1 || (om1 == m1 && oi1 < i1)) {
                    m2 = fmaxf(m1, om2); m1 = om1; i1 = oi1;
                } else {
                    m2 = fmaxf(om1, m2);
                }
            }
            if (fr == 0) {
                size_t o = ((size_t)(b * NN + row) * 32 + t32) * 4;
                *(float4*)&part[o] = (float4){m1, m2, (float)i1, 0.f};
            }
        }
    }
}

// ---------------------------------------------------------------------------
// K2: merge partials -> corres0, flags; push PRUNED (row,tile) refine items;
// gather corrTgt = tgt[:, corres0]
// ---------------------------------------------------------------------------
__global__ __launch_bounds__(256) void combine_rows(const float* __restrict__ part,
                                                    const float* __restrict__ tgtP,
                                                    int* __restrict__ corres,
                                                    int* __restrict__ flags,
                                                    int* __restrict__ list,
                                                    int* __restrict__ count,
                                                    unsigned long long* __restrict__ keys,
                                                    float* __restrict__ corrTgt) {
    int b = blockIdx.y;
    int w = threadIdx.x >> 6, lane = threadIdx.x & 63;
    int n = blockIdx.x * 4 + w;
    int row = b * NN + n;
    float m1 = -3.4e38f, m2 = -3.4e38f;
    int i1 = 0x7fffffff;
    if (lane < 32) {
        float4 p1 = *(const float4*)&part[((size_t)row * 32 + lane) * 4];
        m1 = p1.x; m2 = p1.y; i1 = (int)p1.z;
    }
    float tm1 = m1;  // per-lane tile max, preserved through the reduction
#pragma unroll
    for (int st = 1; st < 64; st <<= 1) {
        float om1 = __shfl_xor(m1, st, 64);
        float om2 = __shfl_xor(m2, st, 64);
        int oi1 = __shfl_xor(i1, st, 64);
        if (om1 > m1 || (om1 == m1 && oi1 < i1)) {
            m2 = fmaxf(m1, om2); m1 = om1; i1 = oi1;
        } else {
            m2 = fmaxf(om1, m2);
        }
    }
    // fp16 1-product error sigma ~4.7 sv per score; flag if gap < 34 (~5 sigma)
    int fl = (__fsub_rn(m1, m2) < 34.0f) ? 1 : 0;
    // tile-prune: margin must cover |err(c1)|+|err(c*)| (sigma~6.6) -> 44
    bool pred = fl && (lane < 32) && (tm1 >= __fsub_rn(m1, 44.0f));
    unsigned long long mask = __ballot(pred);
    int base = 0;
    if (fl) {
        if (lane == 0) {
            flags[row] = 1;
            keys[row] = 0ull;  // refine runs later in stream order
            base = atomicAdd(count, __popcll(mask));
        }
        base = __shfl(base, 0, 64);
        if (pred) {
            int rank = __popcll(mask & ((1ull << lane) - 1ull));
            list[base + rank] = (row << 5) | lane;  // (row, tile)
        }
    } else if (lane == 0) {
        flags[row] = 0;
    }
    if (lane == 0) {
        corres[row] = i1;
        const float* tb = tgtP + (size_t)b * 3 * NN;
        corrTgt[(size_t)row * 3 + 0] = tb[i1];
        corrTgt[(size_t)row * 3 + 1] = tb[NN + i1];
        corrTgt[(size_t)row * 3 + 2] = tb[2 * NN + i1];
    }
}

// ---------------------------------------------------------------------------
// K2b: tile-pruned exact-f32 argmax refine. Item = (row, 64-col tile);
// 256 threads = 64 cols x 4-way K-split; A-col in LDS; atomicMax packed key.
// ---------------------------------------------------------------------------
__global__ __launch_bounds__(256) void refine_tiles(const float* __restrict__ A,
                                                    const float* __restrict__ Bm,
                                                    const int* __restrict__ list,
                                                    const int* __restrict__ count,
                                                    unsigned long long* __restrict__ keys) {
    int tid = threadIdx.x;
    int c = tid & 63, ks = tid >> 6;
    __shared__ float Acol[DD];
    __shared__ float partial[4][64];
    int nitems = count[0];
    for (int item = blockIdx.x; item < nitems; item += 2048) {
        int code = list[item];
        int row = code >> 5, tile = code & 31;
        int b = row / NN, n = row % NN;
        const float* Ab = A + (size_t)b * DD * NN;
        const float* Bb = Bm + (size_t)b * DD * NN;
        Acol[tid] = Ab[(size_t)tid * NN + n];
        Acol[tid + 256] = Ab[(size_t)(tid + 256) * NN + n];
        __syncthreads();
        int m = tile * 64 + c;
        float acc = 0.f;
        int dbase = ks * 128;
        for (int d = 0; d < 128; d++)
            acc = fmaf(Acol[dbase + d], Bb[(size_t)(dbase + d) * NN + m], acc);
        partial[ks][c] = acc;
        __syncthreads();
        if (tid < 64) {  // one wave finishes: sum K-splits, pack key, reduce
            float tot = __fadd_rn(__fadd_rn(partial[0][c], partial[1][c]),
                                  __fadd_rn(partial[2][c], partial[3][c]));
            float sc = __fmul_rn(10000.0f, __fdiv_rn(tot, 22.627416997969522f));
            unsigned u = __float_as_uint(sc);
            u = (u & 0x80000000u) ? ~u : (u | 0x80000000u);  // order-preserving
            unsigned long long key =
                ((unsigned long long)u << 32) | (unsigned)(~(unsigned)m);
#pragma unroll
            for (int st = 1; st < 64; st <<= 1) {
                unsigned long long ok = __shfl_xor((long long)key, st, 64);
                if (ok > key) key = ok;
            }
            if (c == 0) atomicMax(&keys[row], key);
        }
        __syncthreads();
    }
}

// ---------------------------------------------------------------------------
// K3: GFM — 512 threads, 2 points/wave (16/block): shared XP b128 reads,
// packed u32 selection keys (bit-identical to prior round per point).
// ---------------------------------------------------------------------------
__global__ __launch_bounds__(512) void gfm_kernel(const float* __restrict__ srcP,
                                                  const float* __restrict__ corrTgt,
                                                  float* __restrict__ pointLoss) {
    int b = blockIdx.y, tid = threadIdx.x;
    int w = tid >> 6, lane = tid & 63;
    int nbase = blockIdx.x * 16 + w * 2;
    __shared__ float4 XP[NN];  // {x, y, z, sq} = 32 KB
    __shared__ int nbl[16][KNB];
    __shared__ float ptb[16][KNB][3];
    __shared__ float la[16][NPAIR], rg[16][NPAIR], srt[16][NPAIR];
    const float* xs = srcP + (size_t)b * 3 * NN;

    for (int i = tid; i < NN / 4; i += 512) {
        float4 u0 = ((const float4*)xs)[i];
        float4 u1 = ((const float4*)(xs + NN))[i];
        float4 u2 = ((const float4*)(xs + 2 * NN))[i];
        float4 q;
        q.x = __fadd_rn(__fadd_rn(__fmul_rn(u0.x, u0.x), __fmul_rn(u1.x, u1.x)), __fmul_rn(u2.x, u2.x));
        q.y = __fadd_rn(__fadd_rn(__fmul_rn(u0.y, u0.y), __fmul_rn(u1.y, u1.y)), __fmul_rn(u2.y, u2.y));
        q.z = __fadd_rn(__fadd_rn(__fmul_rn(u0.z, u0.z), __fmul_rn(u1.z, u1.z)), __fmul_rn(u2.z, u2.z));
        q.w = __fadd_rn(__fadd_rn(__fmul_rn(u0.w, u0.w), __fmul_rn(u1.w, u1.w)), __fmul_rn(u2.w, u2.w));
        XP[4 * i + 0] = (float4){u0.x, u1.x, u2.x, q.x};
        XP[4 * i + 1] = (float4){u0.y, u1.y, u2.y, q.y};
        XP[4 * i + 2] = (float4){u0.z, u1.z, u2.z, q.z};
        XP[4 * i + 3] = (float4){u0.w, u1.w, u2.w, q.w};
    }
    __syncthreads();

    float4 av[2];
    av[0] = XP[nbase];
    av[1] = XP[nbase + 1];
    unsigned key[2][32];
#pragma unroll
    for (int r = 0; r < 32; r++) {
        int m = lane + 64 * r;
        float4 p = XP[m];  // shared load serves both anchors
#pragma unroll
        for (int pp = 0; pp < 2; pp++) {
            float dot = __fadd_rn(__fadd_rn(__fmul_rn(av[pp].x, p.x), __fmul_rn(av[pp].y, p.y)),
                                  __fmul_rn(av[pp].z, p.z));
            float d2 = __fsub_rn(__fadd_rn(av[pp].w, p.w), __fmul_rn(2.0f, dot));
            d2 = fmaxf(d2, 0.0f);
            key[pp][r] = (__float_as_uint(d2) & 0xFFFFF800u) | (unsigned)m;
        }
    }

#pragma unroll
    for (int pp = 0; pp < 2; pp++) {
        int slot = w * 2 + pp;
        int n = nbase + pp;
        float a0 = av[pp].x, a1 = av[pp].y, a2 = av[pp].z;

        unsigned removed = 0;
#pragma unroll
        for (int it = 0; it < KNB; it++) {
            unsigned best = 0xFFFFFFFFu;
#pragma unroll
            for (int r = 0; r < 32; r++) {
                unsigned kk = ((removed >> r) & 1u) ? 0xFFFFFFFFu : key[pp][r];
                best = min(best, kk);
            }
#pragma unroll
            for (int st = 1; st < 64; st <<= 1) {
                unsigned ob = __shfl_xor((int)best, st, 64);
                best = min(best, ob);
            }
            int m = (int)(best & 2047u);
            if (lane == 0) nbl[slot][it] = m;
            removed |= ((m & 63) == lane) ? (1u << (m >> 6)) : 0u;
        }
        __builtin_amdgcn_wave_barrier();
        if (lane < KNB) {
            int ia = nbl[slot][lane];
            const float* ct = corrTgt + ((size_t)b * NN + ia) * 3;
            ptb[slot][lane][0] = ct[0];
            ptb[slot][lane][1] = ct[1];
            ptb[slot][lane][2] = ct[2];
        }
        __builtin_amdgcn_wave_barrier();
        const float* ctn = corrTgt + ((size_t)b * NN + n) * 3;
        float t0 = ctn[0], t1 = ctn[1], t2 = ctn[2];
        if (lane < NPAIR) {
            int k = lane, ja = 0, cnt = 9;
            while (k >= cnt) { k -= cnt; ja++; cnt--; }
            int jb = ja + 1 + k;
            int ia = nbl[slot][ja], ib = nbl[slot][jb];
            float4 pa = XP[ia], pb = XP[ib];
            float area_s = tri_area(a0, a1, a2, pa.x, pa.y, pa.z, pb.x, pb.y, pb.z);
            float area_t = tri_area(t0, t1, t2, ptb[slot][ja][0], ptb[slot][ja][1],
                                    ptb[slot][ja][2], ptb[slot][jb][0], ptb[slot][jb][1],
                                    ptb[slot][jb][2]);
            const float EPSF = 1e-6f;
            float ee = __fmul_rn(EPSF, EPSF);
            float lt2 = __fadd_rn(area_t, EPSF);
            float da = __fsub_rn(area_s, lt2);
            float sa = __fadd_rn(area_s, lt2);
            float num = __fadd_rn(__fadd_rn(ee, ee), __fmul_rn(da, da));
            float den = __fadd_rn(__fadd_rn(ee, ee), __fmul_rn(sa, sa));
            la[slot][lane] = __fdiv_rn(num, den);
            rg[slot][lane] = sqrtf(num);
        }
        __builtin_amdgcn_wave_barrier();
        if (lane < NPAIR) {  // stable rank sort #1
            float x = la[slot][lane];
            int rk = 0;
            for (int j = 0; j < NPAIR; j++) {
                float y = la[slot][j];
                rk += (y < x || (y == x && j < lane)) ? 1 : 0;
            }
            srt[slot][rk] = x;
        }
        __builtin_amdgcn_wave_barrier();
        float l2v = 0.f;
        if (lane < NPAIR) l2v = __fadd_rn(srt[slot][lane], __fmul_rn(0.1f, rg[slot][lane]));
        __builtin_amdgcn_wave_barrier();
        if (lane < NPAIR) la[slot][lane] = l2v;
        __builtin_amdgcn_wave_barrier();
        if (lane < NPAIR) {  // stable rank sort #2
            float x = la[slot][lane];
            int rk = 0;
            for (int j = 0; j < NPAIR; j++) {
                float y = la[slot][j];
                rk += (y < x || (y == x && j < lane)) ? 1 : 0;
            }
            srt[slot][rk] = x;
        }
        __builtin_amdgcn_wave_barrier();
        float med = srt[slot][22];
        float thr = __fmul_rn(3.0f, med);
        float term = 0.f;
        if (lane < KNB) {
            float vv = la[slot][lane];
            if (vv > thr) vv = 0.f;
            term = sqrtf(__fadd_rn(vv, 1e-6f));
        }
#pragma unroll
        for (int st = 1; st < 64; st <<= 1) term += __shfl_xor(term, st, 64);
        if (lane == 0) pointLoss[b * NN + n] = __fdiv_rn(term, 10.0f);
    }
}

// ---------------------------------------------------------------------------
// K4: fused finish — 1024 threads/batch: refined corres, min, weight,
// Procrustes reductions, 3x3 Jacobi SVD
// ---------------------------------------------------------------------------
__device__ double det3(const double M[3][3]) {
    return M[0][0] * (M[1][1] * M[2][2] - M[1][2] * M[2][1]) -
           M[0][1] * (M[1][0] * M[2][2] - M[1][2] * M[2][0]) +
           M[0][2] * (M[1][0] * M[2][1] - M[1][1] * M[2][0]);
}

__global__ __launch_bounds__(1024) void fused_finish(const float* __restrict__ pointLoss,
                                                     const int* __restrict__ flags,
                                                     const unsigned long long* __restrict__ keys,
                                                     const int* __restrict__ corresIn,
                                                     const float* __restrict__ srcP,
                                                     const float* __restrict__ tgtP,
                                                     float* __restrict__ outR,
                                                     float* __restrict__ outT,
                                                     float* __restrict__ outC,
                                                     float* __restrict__ outW) {
    int b = blockIdx.x, tid = threadIdx.x;
    int w = tid >> 6, lane = tid & 63;
    __shared__ int csh[NN];
    __shared__ float wsh[NN];
    __shared__ float fred[1024];
    __shared__ double sd[16][9];
    __shared__ double sxySh[9];

    // phase 1: final corres (apply refined keys) + min(pointLoss)
    float mn = 3.4e38f;
    for (int n = tid; n < NN; n += 1024) {
        int row = b * NN + n;
        int ci = corresIn[row];
        if (flags[row]) ci = (int)(~(unsigned)(keys[row] & 0xFFFFFFFFull));
        csh[n] = ci;
        outC[row] = (float)ci;
        mn = fminf(mn, pointLoss[row]);
    }
    fred[tid] = mn;
    __syncthreads();
    for (int st = 512; st > 0; st >>= 1) {
        if (tid < st) fred[tid] = fminf(fred[tid], fred[tid + st]);
        __syncthreads();
    }
    float minL = fred[0];
    __syncthreads();

    // phase 2: weight
    for (int n = tid; n < NN; n += 1024) {
        int row = b * NN + n;
        float l = __fsub_rn(pointLoss[row], minL);
        float z = __fmul_rn(-20.0f, l);
        float ez = expf(z);
        float sg = __fdiv_rn(ez, __fadd_rn(1.0f, ez));
        float wf = (__fmul_rn(2.0f, sg) > 0.5f) ? 1.0f : 0.0f;
        wsh[n] = wf;
        outW[row] = wf;
    }
    __syncthreads();

    // phase 3: Procrustes reductions (double, 16 waves)
    const float* xs = srcP + (size_t)b * 3 * NN;
    const float* ts = tgtP + (size_t)b * 3 * NN;
    double acc7[7] = {0, 0, 0, 0, 0, 0, 0};
    for (int n = tid; n < NN; n += 1024) {
        if (wsh[n] != 0.0f) {
            acc7[0] += 1.0;
            acc7[1] += (double)xs[n];
            acc7[2] += (double)xs[NN + n];
            acc7[3] += (double)xs[2 * NN + n];
            int m = csh[n];
            acc7[4] += (double)ts[m];
            acc7[5] += (double)ts[NN + m];
            acc7[6] += (double)ts[2 * NN + m];
        }
    }
#pragma unroll
    for (int q = 0; q < 7; q++) {
        double r = wave_red_sum_d(acc7[q]);
        if (lane == 0) sd[w][q] = r;
    }
    __syncthreads();
    double tot7[7];
#pragma unroll
    for (int q = 0; q < 7; q++) {
        double s2 = 0;
#pragma unroll
        for (int w2 = 0; w2 < 16; w2++) s2 += sd[w2][q];
        tot7[q] = s2;
    }
    __syncthreads();

    double W1e = tot7[0] + 1e-7;
    double mux0 = tot7[1] / W1e, mux1 = tot7[2] / W1e, mux2 = tot7[3] / W1e;
    double muy0 = tot7[4] / W1e, muy1 = tot7[5] / W1e, muy2 = tot7[6] / W1e;

    double s[9] = {0, 0, 0, 0, 0, 0, 0, 0, 0};
    for (int n = tid; n < NN; n += 1024) {
        if (wsh[n] != 0.0f) {
            double dx0 = (double)xs[n] - mux0;
            double dx1 = (double)xs[NN + n] - mux1;
            double dx2 = (double)xs[2 * NN + n] - mux2;
            int m = csh[n];
            double dy0 = (double)ts[m] - muy0;
            double dy1 = (double)ts[NN + m] - muy1;
            double dy2 = (double)ts[2 * NN + m] - muy2;
            s[0] += dy0 * dx0; s[1] += dy0 * dx1; s[2] += dy0 * dx2;
            s[3] += dy1 * dx0; s[4] += dy1 * dx1; s[5] += dy1 * dx2;
            s[6] += dy2 * dx0; s[7] += dy2 * dx1; s[8] += dy2 * dx2;
        }
    }
#pragma unroll
    for (int q = 0; q < 9; q++) {
        double r = wave_red_sum_d(s[q]);
        if (lane == 0) sd[w][q] = r;
    }
    __syncthreads();
    if (tid < 9) {
        double s2 = 0;
#pragma unroll
        for (int w2 = 0; w2 < 16; w2++) s2 += sd[w2][tid];
        sxySh[tid] = s2 / W1e;
    }
    __syncthreads();

    // phase 4: one thread does the 3x3 Jacobi SVD -> R, T
    if (tid == 0) {
        double Bm2[3][3], V[3][3];
        for (int r = 0; r < 3; r++)
            for (int c2 = 0; c2 < 3; c2++) {
                Bm2[r][c2] = sxySh[r * 3 + c2];
                V[r][c2] = (r == c2) ? 1.0 : 0.0;
            }
        double nrm2 = 0;
        for (int r = 0; r < 3; r++)
            for (int c2 = 0; c2 < 3; c2++) nrm2 += Bm2[r][c2] * Bm2[r][c2];

        for (int sweep = 0; sweep < 60; sweep++) {
            double off = 0;
            for (int p = 0; p < 2; p++) {
                for (int q = p + 1; q < 3; q++) {
                    double al = 0, be = 0, ga = 0;
                    for (int i = 0; i < 3; i++) {
                        al += Bm2[i][p] * Bm2[i][p];
                        be += Bm2[i][q] * Bm2[i][q];
                        ga += Bm2[i][p] * Bm2[i][q];
                    }
                    off += ga * ga;
                    if (fabs(ga) > 1e-300) {
                        double ze = (be - al) / (2.0 * ga);
                        double tt = copysign(1.0, ze) / (fabs(ze) + sqrt(1.0 + ze * ze));
                        double c = 1.0 / sqrt(1.0 + tt * tt), sn = c * tt;
                        for (int i = 0; i < 3; i++) {
                            double bp = Bm2[i][p], bq = Bm2[i][q];
                            Bm2[i][p] = c * bp - sn * bq;
                            Bm2[i][q] = sn * bp + c * bq;
                            double vp = V[i][p], vq = V[i][q];
                            V[i][p] = c * vp - sn * vq;
                            V[i][q] = sn * vp + c * vq;
                        }
                    }
                }
            }
            if (off <= 1e-30 * nrm2 * nrm2) break;
        }
        double sig[3];
        for (int j = 0; j < 3; j++) {
            double ss = 0;
            for (int i = 0; i < 3; i++) ss += Bm2[i][j] * Bm2[i][j];
            sig[j] = sqrt(ss);
        }
        for (int a = 0; a < 2; a++)
            for (int j = 0; j < 2 - a; j++)
                if (sig[j] < sig[j + 1]) {
                    double t2 = sig[j]; sig[j] = sig[j + 1]; sig[j + 1] = t2;
                    for (int i = 0; i < 3; i++) {
                        double tb = Bm2[i][j]; Bm2[i][j] = Bm2[i][j + 1]; Bm2[i][j + 1] = tb;
                        double tv = V[i][j]; V[i][j] = V[i][j + 1]; V[i][j + 1] = tv;
                    }
                }
        double U[3][3];
        for (int j = 0; j < 3; j++) {
            double inv = (sig[j] > 1e-150) ? 1.0 / sig[j] : 0.0;
            for (int i = 0; i < 3; i++) U[i][j] = Bm2[i][j] * inv;
        }
        if (sig[2] <= 1e-10 * (sig[0] + 1e-300)) {
            double u0 = U[1][0] * U[2][1] - U[2][0] * U[1][1];
            double u1 = U[2][0] * U[0][1] - U[0][0] * U[2][1];
            double u2 = U[0][0] * U[1][1] - U[1][0] * U[0][1];
            double nr = sqrt(u0 * u0 + u1 * u1 + u2 * u2);
            if (nr > 1e-150) { U[0][2] = u0 / nr; U[1][2] = u1 / nr; U[2][2] = u2 / nr; }
        }
        double dU = det3(U), dV = det3(V);
        double s3 = (dU * dV >= 0.0) ? 1.0 : -1.0;
        double R[3][3];
        for (int i = 0; i < 3; i++)
            for (int j = 0; j < 3; j++)
                R[i][j] = U[i][0] * V[j][0] + U[i][1] * V[j][1] + s3 * U[i][2] * V[j][2];
        double mux[3] = {mux0, mux1, mux2};
        double muy[3] = {muy0, muy1, muy2};
        for (int i = 0; i < 3; i++) {
            for (int j = 0; j < 3; j++) outR[b * 9 + i * 3 + j] = (float)R[i][j];
            double t2 = muy[i] - (R[i][0] * mux[0] + R[i][1] * mux[1] + R[i][2] * mux[2]);
            outT[b * 3 + i] = (float)t2;
        }
    }
}

// ---------------------------------------------------------------------------
// host launcher
// ---------------------------------------------------------------------------
extern "C" void kernel_launch(void* const* d_in, const int* in_sizes, int n_in,
                              void* d_out, int out_size, void* d_ws, size_t ws_size,
                              hipStream_t stream) {
    const float* srcE = (const float*)d_in[0];
    const float* tgtE = (const float*)d_in[1];
    const float* srcP = (const float*)d_in[2];
    const float* tgtP = (const float*)d_in[3];
    float* out = (float*)d_out;  // R[36] T[12] corres[8192] weight[8192]

    char* w = (char*)d_ws;
    size_t off = 0;
    auto alloc = [&](size_t bytes) -> void* {
        void* p = w + off;
        off = (off + bytes + 255) & ~(size_t)255;
        return p;
    };
    float* corrTgt = (float*)alloc((size_t)NBATCH * NN * 3 * 4);
    int* corres = (int*)alloc((size_t)NBATCH * NN * 4);
    int* flags = (int*)alloc((size_t)NBATCH * NN * 4);
    unsigned long long* keys = (unsigned long long*)alloc((size_t)NBATCH * NN * 8);
    int* list = (int*)alloc((size_t)NBATCH * NN * 32 * 4);  // worst-case all tiles
    int* count = (int*)alloc(256);
    float* pointLoss = (float*)alloc((size_t)NBATCH * NN * 4);
    size_t planeShorts = (size_t)NBATCH * 16 * NN * 32;  // 8.4 MB per plane
    short* Ah = (short*)alloc(planeShorts * 2);
    short* Bh = (short*)alloc(planeShorts * 2);
    float* part = (float*)alloc((size_t)NBATCH * NN * 32 * 4 * 4);  // 4.2 MB

    prep_planes<<<dim3(512, NBATCH, 2), 256, 0, stream>>>(srcE, tgtE, Ah, Bh, count);
    gemm_fused<<<dim3(NN / 128, NN / 128, NBATCH), 256, 0, stream>>>(Ah, Bh, part);
    combine_rows<<<dim3(NN / 4, NBATCH), 256, 0, stream>>>(part, tgtP, corres, flags, list,
                                                           count, keys, corrTgt);
    gfm_kernel<<<dim3(NN / 16, NBATCH), 512, 0, stream>>>(srcP, corrTgt, pointLoss);
    refine_tiles<<<dim3(2048), 256, 0, stream>>>(srcE, tgtE, list, count, keys);
    fused_finish<<<NBATCH, 1024, 0, stream>>>(pointLoss, flags, keys, corres, srcP, tgtP,
                                              out, out + 36, out + 48, out + 48 + NBATCH * NN);
}

// Round 16
// 131.724 us; speedup vs baseline: 1.0984x; 1.0984x over previous
//
#include <hip/hip_runtime.h>
#include <hip/hip_bf16.h>

#define NN 2048
#define DD 512
#define NBATCH 4
#define KNB 10
#define NPAIR 45

typedef __attribute__((ext_vector_type(8))) _Float16 f16x8;
typedef __attribute__((ext_vector_type(4))) float f32x4;

// ---------------------------------------------------------------------------
// helpers
// ---------------------------------------------------------------------------
__device__ __forceinline__ float tri_area(float p0x, float p0y, float p0z,
                                          float p1x, float p1y, float p1z,
                                          float p2x, float p2y, float p2z) {
    float e1x = __fsub_rn(p1x, p0x), e1y = __fsub_rn(p1y, p0y), e1z = __fsub_rn(p1z, p0z);
    float e2x = __fsub_rn(p2x, p0x), e2y = __fsub_rn(p2y, p0y), e2z = __fsub_rn(p2z, p0z);
    float c0 = __fsub_rn(__fmul_rn(e1y, e2z), __fmul_rn(e1z, e2y));
    float c1 = __fsub_rn(__fmul_rn(e1z, e2x), __fmul_rn(e1x, e2z));
    float c2 = __fsub_rn(__fmul_rn(e1x, e2y), __fmul_rn(e1y, e2x));
    float ss = __fadd_rn(__fadd_rn(__fmul_rn(c0, c0), __fmul_rn(c1, c1)), __fmul_rn(c2, c2));
    return __fmul_rn(0.5f, sqrtf(ss));
}

__device__ __forceinline__ double wave_red_sum_d(double v) {
#pragma unroll
    for (int st = 1; st < 64; st <<= 1) v += __shfl_xor(v, st, 64);
    return v;
}

// ---------------------------------------------------------------------------
// K0: prep_planes — f32 -> fp16 h plane, pre-tiled + pre-swizzled.
// Coalesced lane map: n = ng*64 + (t&63), gg = t>>6 (256B segments).
// Also zeroes `count`.
// ---------------------------------------------------------------------------
__global__ __launch_bounds__(256) void prep_planes(const float* __restrict__ srcE,
                                                   const float* __restrict__ tgtE,
                                                   short* __restrict__ Ah,
                                                   short* __restrict__ Bh,
                                                   int* __restrict__ count) {
    int kt = blockIdx.x & 15, ng = blockIdx.x >> 4;
    int b = blockIdx.y, mat = blockIdx.z;
    int t = threadIdx.x;
    if (blockIdx.x == 0 && b == 0 && mat == 0 && t == 0) count[0] = 0;
    int nloc = t & 63, gg = t >> 6;
    int n = ng * 64 + nloc;
    int d0 = kt * 32 + gg * 8;
    const float* src = (mat ? tgtE : srcE) + (size_t)b * DD * NN;
    short* PH = mat ? Bh : Ah;

    float x[8];
#pragma unroll
    for (int j = 0; j < 8; j++) x[j] = src[(size_t)(d0 + j) * NN + n];
    unsigned h4[4];
#pragma unroll
    for (int p = 0; p < 4; p++) {
        _Float16 h0 = (_Float16)x[2 * p], h1 = (_Float16)x[2 * p + 1];  // RNE
        h4[p] = (unsigned)__builtin_bit_cast(unsigned short, h0) |
                ((unsigned)__builtin_bit_cast(unsigned short, h1) << 16);
    }
    size_t o = ((size_t)(b * 16 + kt) * NN + n) * 32 + ((gg ^ ((n >> 1) & 3)) << 3);
    *(uint4*)&PH[o] = (uint4){h4[0], h4[1], h4[2], h4[3]};
}

// ---------------------------------------------------------------------------
// K1: 2-phase double-buffered MFMA GEMM (fp16 1-product) + top-2/argmax
// epilogue.  (verified; at the 2-barrier structure floor)
// ---------------------------------------------------------------------------
__global__ __launch_bounds__(256) void gemm_fused(const short* __restrict__ Ah,
                                                  const short* __restrict__ Bh,
                                                  float* __restrict__ part) {
    int b = blockIdx.z;
    int id = blockIdx.y * 16 + blockIdx.x;
    int swz = (id & 7) * 32 + (id >> 3);  // XCD-bijective (256 % 8 == 0)
    int bx = swz & 15, by = swz >> 4;
    int n0 = by * 128, m0 = bx * 128;

    __shared__ short LDS[2][2][4096];  // [buf][plane: Ah Bh] = 32 KB

    int t = threadIdx.x, w = t >> 6, lane = t & 63;
    int wr = w >> 1, wc = w & 1;
    int fr = lane & 15, kq = lane >> 4;

    const short* gpl[2] = {Ah, Bh};

    f32x4 acc[4][4];
#pragma unroll
    for (int i = 0; i < 4; i++)
#pragma unroll
        for (int j = 0; j < 4; j++) acc[i][j] = (f32x4){0.f, 0.f, 0.f, 0.f};

    auto STAGE = [&](int buf, int kt) {
#pragma unroll
        for (int q = 0; q < 4; q++) {
            int p = q >> 1, h = q & 1;
            int rb = (p == 0) ? n0 : m0;
            const short* g = gpl[p] + ((size_t)(b * 16 + kt) * NN + rb) * 32 +
                             h * 2048 + w * 512 + lane * 8;
            __builtin_amdgcn_global_load_lds(
                (const __attribute__((address_space(1))) void*)g,
                (__attribute__((address_space(3))) void*)&LDS[buf][p][h * 2048 + w * 512],
                16, 0, 0);
        }
    };

    STAGE(0, 0);
    __syncthreads();
    int cur = 0;
    for (int kt = 0; kt < 16; kt++) {
        if (kt < 15) STAGE(cur ^ 1, kt + 1);  // next tile in flight over compute

        f16x8 ah[4], bh[4];
#pragma unroll
        for (int i = 0; i < 4; i++) {
            int rA = wr * 64 + i * 16 + fr;
            int offA = rA * 32 + ((kq ^ ((rA >> 1) & 3)) << 3);
            ah[i] = *(const f16x8*)&LDS[cur][0][offA];
            int rB = wc * 64 + i * 16 + fr;
            int offB = rB * 32 + ((kq ^ ((rB >> 1) & 3)) << 3);
            bh[i] = *(const f16x8*)&LDS[cur][1][offB];
        }
#pragma unroll
        for (int i = 0; i < 4; i++)
#pragma unroll
            for (int j = 0; j < 4; j++)
                acc[i][j] = __builtin_amdgcn_mfma_f32_16x16x32_f16(ah[i], bh[j],
                                                                   acc[i][j], 0, 0, 0);
        __syncthreads();
        cur ^= 1;
    }

    // ---- top-2/argmax epilogue ----
    int t32 = bx * 2 + wc;
#pragma unroll
    for (int i = 0; i < 4; i++) {
#pragma unroll
        for (int rg = 0; rg < 4; rg++) {
            int row = n0 + wr * 64 + i * 16 + kq * 4 + rg;
            float m1 = -3.4e38f, m2 = -3.4e38f;
            int i1 = 0x7fffffff;
#pragma unroll
            for (int j = 0; j < 4; j++) {
                float vv = __fmul_rn(10000.0f, __fdiv_rn(acc[i][j][rg], 22.627416997969522f));
                int col = m0 + wc * 64 + j * 16 + fr;
                if (vv > m1) { m2 = m1; m1 = vv; i1 = col; }
                else if (vv > m2) m2 = vv;
            }
#pragma unroll
            for (int st = 1; st < 16; st <<= 1) {
                float om1 = __shfl_xor(m1, st, 64);
                float om2 = __shfl_xor(m2, st, 64);
                int oi1 = __shfl_xor(i1, st, 64);
                if (om1 > m1 || (om1 == m1 && oi1 < i1)) {
                    m2 = fmaxf(m1, om2); m1 = om1; i1 = oi1;
                } else {
                    m2 = fmaxf(om1, m2);
                }
            }
            if (fr == 0) {
                size_t o = ((size_t)(b * NN + row) * 32 + t32) * 4;
                *(float4*)&part[o] = (float4){m1, m2, (float)i1, 0.f};
            }
        }
    }
}

// ---------------------------------------------------------------------------
// K2: merge partials -> corres0, flags; push PRUNED (row,tile) refine items;
// gather corrTgt = tgt[:, corres0]
// ---------------------------------------------------------------------------
__global__ __launch_bounds__(256) void combine_rows(const float* __restrict__ part,
                                                    const float* __restrict__ tgtP,
                                                    int* __restrict__ corres,
                                                    int* __restrict__ flags,
                                                    int* __restrict__ list,
                                                    int* __restrict__ count,
                                                    unsigned long long* __restrict__ keys,
                                                    float* __restrict__ corrTgt) {
    int b = blockIdx.y;
    int w = threadIdx.x >> 6, lane = threadIdx.x & 63;
    int n = blockIdx.x * 4 + w;
    int row = b * NN + n;
    float m1 = -3.4e38f, m2 = -3.4e38f;
    int i1 = 0x7fffffff;
    if (lane < 32) {
        float4 p1 = *(const float4*)&part[((size_t)row * 32 + lane) * 4];
        m1 = p1.x; m2 = p1.y; i1 = (int)p1.z;
    }
    float tm1 = m1;  // per-lane tile max, preserved through the reduction
#pragma unroll
    for (int st = 1; st < 64; st <<= 1) {
        float om1 = __shfl_xor(m1, st, 64);
        float om2 = __shfl_xor(m2, st, 64);
        int oi1 = __shfl_xor(i1, st, 64);
        if (om1 > m1 || (om1 == m1 && oi1 < i1)) {
            m2 = fmaxf(m1, om2); m1 = om1; i1 = oi1;
        } else {
            m2 = fmaxf(om1, m2);
        }
    }
    // fp16 1-product error sigma ~4.7 sv per score; flag if gap < 34 (~5 sigma)
    int fl = (__fsub_rn(m1, m2) < 34.0f) ? 1 : 0;
    // tile-prune: margin must cover |err(c1)|+|err(c*)| (sigma~6.6) -> 44
    bool pred = fl && (lane < 32) && (tm1 >= __fsub_rn(m1, 44.0f));
    unsigned long long mask = __ballot(pred);
    int base = 0;
    if (fl) {
        if (lane == 0) {
            flags[row] = 1;
            keys[row] = 0ull;  // refine runs later in stream order
            base = atomicAdd(count, __popcll(mask));
        }
        base = __shfl(base, 0, 64);
        if (pred) {
            int rank = __popcll(mask & ((1ull << lane) - 1ull));
            list[base + rank] = (row << 5) | lane;  // (row, tile)
        }
    } else if (lane == 0) {
        flags[row] = 0;
    }
    if (lane == 0) {
        corres[row] = i1;
        const float* tb = tgtP + (size_t)b * 3 * NN;
        corrTgt[(size_t)row * 3 + 0] = tb[i1];
        corrTgt[(size_t)row * 3 + 1] = tb[NN + i1];
        corrTgt[(size_t)row * 3 + 2] = tb[2 * NN + i1];
    }
}

// ---------------------------------------------------------------------------
// K2b: tile-pruned exact-f32 argmax refine. Item = (row, 64-col tile);
// 256 threads = 64 cols x 4-way K-split; A-col in LDS; atomicMax packed key.
// ---------------------------------------------------------------------------
__global__ __launch_bounds__(256) void refine_tiles(const float* __restrict__ A,
                                                    const float* __restrict__ Bm,
                                                    const int* __restrict__ list,
                                                    const int* __restrict__ count,
                                                    unsigned long long* __restrict__ keys) {
    int tid = threadIdx.x;
    int c = tid & 63, ks = tid >> 6;
    __shared__ float Acol[DD];
    __shared__ float partial[4][64];
    int nitems = count[0];
    for (int item = blockIdx.x; item < nitems; item += 2048) {
        int code = list[item];
        int row = code >> 5, tile = code & 31;
        int b = row / NN, n = row % NN;
        const float* Ab = A + (size_t)b * DD * NN;
        const float* Bb = Bm + (size_t)b * DD * NN;
        Acol[tid] = Ab[(size_t)tid * NN + n];
        Acol[tid + 256] = Ab[(size_t)(tid + 256) * NN + n];
        __syncthreads();
        int m = tile * 64 + c;
        float acc = 0.f;
        int dbase = ks * 128;
        for (int d = 0; d < 128; d++)
            acc = fmaf(Acol[dbase + d], Bb[(size_t)(dbase + d) * NN + m], acc);
        partial[ks][c] = acc;
        __syncthreads();
        if (tid < 64) {  // one wave finishes: sum K-splits, pack key, reduce
            float tot = __fadd_rn(__fadd_rn(partial[0][c], partial[1][c]),
                                  __fadd_rn(partial[2][c], partial[3][c]));
            float sc = __fmul_rn(10000.0f, __fdiv_rn(tot, 22.627416997969522f));
            unsigned u = __float_as_uint(sc);
            u = (u & 0x80000000u) ? ~u : (u | 0x80000000u);  // order-preserving
            unsigned long long key =
                ((unsigned long long)u << 32) | (unsigned)(~(unsigned)m);
#pragma unroll
            for (int st = 1; st < 64; st <<= 1) {
                unsigned long long ok = __shfl_xor((long long)key, st, 64);
                if (ok > key) key = ok;
            }
            if (c == 0) atomicMax(&keys[row], key);
        }
        __syncthreads();
    }
}

// ---------------------------------------------------------------------------
// K3: GFM — 512 threads, 8 points/block (1 per wave).  AoS float4 cloud in
// LDS (b128 loads) + packed u32 selection keys.  (round-14 verified winner)
// ---------------------------------------------------------------------------
__global__ __launch_bounds__(512) void gfm_kernel(const float* __restrict__ srcP,
                                                  const float* __restrict__ corrTgt,
                                                  float* __restrict__ pointLoss) {
    int b = blockIdx.y, tid = threadIdx.x;
    int w = tid >> 6, lane = tid & 63;
    int n = blockIdx.x * 8 + w;
    __shared__ float4 XP[NN];  // {x, y, z, sq} = 32 KB
    __shared__ int nbl[8][KNB];
    __shared__ float ptb[8][KNB][3];
    __shared__ float la[8][NPAIR], rg[8][NPAIR], srt[8][NPAIR];
    const float* xs = srcP + (size_t)b * 3 * NN;

    for (int i = tid; i < NN / 4; i += 512) {
        float4 u0 = ((const float4*)xs)[i];
        float4 u1 = ((const float4*)(xs + NN))[i];
        float4 u2 = ((const float4*)(xs + 2 * NN))[i];
        float4 q;
        q.x = __fadd_rn(__fadd_rn(__fmul_rn(u0.x, u0.x), __fmul_rn(u1.x, u1.x)), __fmul_rn(u2.x, u2.x));
        q.y = __fadd_rn(__fadd_rn(__fmul_rn(u0.y, u0.y), __fmul_rn(u1.y, u1.y)), __fmul_rn(u2.y, u2.y));
        q.z = __fadd_rn(__fadd_rn(__fmul_rn(u0.z, u0.z), __fmul_rn(u1.z, u1.z)), __fmul_rn(u2.z, u2.z));
        q.w = __fadd_rn(__fadd_rn(__fmul_rn(u0.w, u0.w), __fmul_rn(u1.w, u1.w)), __fmul_rn(u2.w, u2.w));
        XP[4 * i + 0] = (float4){u0.x, u1.x, u2.x, q.x};
        XP[4 * i + 1] = (float4){u0.y, u1.y, u2.y, q.y};
        XP[4 * i + 2] = (float4){u0.z, u1.z, u2.z, q.z};
        XP[4 * i + 3] = (float4){u0.w, u1.w, u2.w, q.w};
    }
    __syncthreads();

    float4 av = XP[n];
    float a0 = av.x, a1 = av.y, a2 = av.z, sqa = av.w;
    unsigned key[32];
#pragma unroll
    for (int r = 0; r < 32; r++) {
        int m = lane + 64 * r;
        float4 p = XP[m];
        float dot = __fadd_rn(__fadd_rn(__fmul_rn(a0, p.x), __fmul_rn(a1, p.y)),
                              __fmul_rn(a2, p.z));
        float d2 = __fsub_rn(__fadd_rn(sqa, p.w), __fmul_rn(2.0f, dot));
        d2 = fmaxf(d2, 0.0f);
        key[r] = (__float_as_uint(d2) & 0xFFFFF800u) | (unsigned)m;
    }
    unsigned removed = 0;
#pragma unroll
    for (int it = 0; it < KNB; it++) {
        unsigned best = 0xFFFFFFFFu;
#pragma unroll
        for (int r = 0; r < 32; r++) {
            unsigned kk = ((removed >> r) & 1u) ? 0xFFFFFFFFu : key[r];
            best = min(best, kk);
        }
#pragma unroll
        for (int st = 1; st < 64; st <<= 1) {
            unsigned ob = __shfl_xor((int)best, st, 64);
            best = min(best, ob);
        }
        int m = (int)(best & 2047u);
        if (lane == 0) nbl[w][it] = m;
        removed |= ((m & 63) == lane) ? (1u << (m >> 6)) : 0u;
    }
    __builtin_amdgcn_wave_barrier();
    if (lane < KNB) {
        int ia = nbl[w][lane];
        const float* ct = corrTgt + ((size_t)b * NN + ia) * 3;
        ptb[w][lane][0] = ct[0];
        ptb[w][lane][1] = ct[1];
        ptb[w][lane][2] = ct[2];
    }
    __builtin_amdgcn_wave_barrier();
    const float* ctn = corrTgt + ((size_t)b * NN + n) * 3;
    float t0 = ctn[0], t1 = ctn[1], t2 = ctn[2];
    if (lane < NPAIR) {
        int k = lane, ja = 0, cnt = 9;
        while (k >= cnt) { k -= cnt; ja++; cnt--; }
        int jb = ja + 1 + k;
        int ia = nbl[w][ja], ib = nbl[w][jb];
        float4 pa = XP[ia], pb = XP[ib];
        float area_s = tri_area(a0, a1, a2, pa.x, pa.y, pa.z, pb.x, pb.y, pb.z);
        float area_t = tri_area(t0, t1, t2, ptb[w][ja][0], ptb[w][ja][1], ptb[w][ja][2],
                                ptb[w][jb][0], ptb[w][jb][1], ptb[w][jb][2]);
        const float EPSF = 1e-6f;
        float ee = __fmul_rn(EPSF, EPSF);
        float lt2 = __fadd_rn(area_t, EPSF);
        float da = __fsub_rn(area_s, lt2);
        float sa = __fadd_rn(area_s, lt2);
        float num = __fadd_rn(__fadd_rn(ee, ee), __fmul_rn(da, da));
        float den = __fadd_rn(__fadd_rn(ee, ee), __fmul_rn(sa, sa));
        la[w][lane] = __fdiv_rn(num, den);
        rg[w][lane] = sqrtf(num);
    }
    __builtin_amdgcn_wave_barrier();
    if (lane < NPAIR) {
        float x = la[w][lane];
        int rk = 0;
        for (int j = 0; j < NPAIR; j++) {
            float y = la[w][j];
            rk += (y < x || (y == x && j < lane)) ? 1 : 0;
        }
        srt[w][rk] = x;
    }
    __builtin_amdgcn_wave_barrier();
    float l2v = 0.f;
    if (lane < NPAIR) l2v = __fadd_rn(srt[w][lane], __fmul_rn(0.1f, rg[w][lane]));
    __builtin_amdgcn_wave_barrier();
    if (lane < NPAIR) la[w][lane] = l2v;
    __builtin_amdgcn_wave_barrier();
    if (lane < NPAIR) {
        float x = la[w][lane];
        int rk = 0;
        for (int j = 0; j < NPAIR; j++) {
            float y = la[w][j];
            rk += (y < x || (y == x && j < lane)) ? 1 : 0;
        }
        srt[w][rk] = x;
    }
    __builtin_amdgcn_wave_barrier();
    float med = srt[w][22];
    float thr = __fmul_rn(3.0f, med);
    float term = 0.f;
    if (lane < KNB) {
        float vv = la[w][lane];
        if (vv > thr) vv = 0.f;
        term = sqrtf(__fadd_rn(vv, 1e-6f));
    }
#pragma unroll
    for (int st = 1; st < 64; st <<= 1) term += __shfl_xor(term, st, 64);
    if (lane == 0) pointLoss[b * NN + n] = __fdiv_rn(term, 10.0f);
}

// ---------------------------------------------------------------------------
// K4: fused finish — 1024 threads/batch: refined corres, min, weight,
// Procrustes reductions, 3x3 Jacobi SVD
// ---------------------------------------------------------------------------
__device__ double det3(const double M[3][3]) {
    return M[0][0] * (M[1][1] * M[2][2] - M[1][2] * M[2][1]) -
           M[0][1] * (M[1][0] * M[2][2] - M[1][2] * M[2][0]) +
           M[0][2] * (M[1][0] * M[2][1] - M[1][1] * M[2][0]);
}

__global__ __launch_bounds__(1024) void fused_finish(const float* __restrict__ pointLoss,
                                                     const int* __restrict__ flags,
                                                     const unsigned long long* __restrict__ keys,
                                                     const int* __restrict__ corresIn,
                                                     const float* __restrict__ srcP,
                                                     const float* __restrict__ tgtP,
                                                     float* __restrict__ outR,
                                                     float* __restrict__ outT,
                                                     float* __restrict__ outC,
                                                     float* __restrict__ outW) {
    int b = blockIdx.x, tid = threadIdx.x;
    int w = tid >> 6, lane = tid & 63;
    __shared__ int csh[NN];
    __shared__ float wsh[NN];
    __shared__ float fred[1024];
    __shared__ double sd[16][9];
    __shared__ double sxySh[9];

    // phase 1: final corres (apply refined keys) + min(pointLoss)
    float mn = 3.4e38f;
    for (int n = tid; n < NN; n += 1024) {
        int row = b * NN + n;
        int ci = corresIn[row];
        if (flags[row]) ci = (int)(~(unsigned)(keys[row] & 0xFFFFFFFFull));
        csh[n] = ci;
        outC[row] = (float)ci;
        mn = fminf(mn, pointLoss[row]);
    }
    fred[tid] = mn;
    __syncthreads();
    for (int st = 512; st > 0; st >>= 1) {
        if (tid < st) fred[tid] = fminf(fred[tid], fred[tid + st]);
        __syncthreads();
    }
    float minL = fred[0];
    __syncthreads();

    // phase 2: weight
    for (int n = tid; n < NN; n += 1024) {
        int row = b * NN + n;
        float l = __fsub_rn(pointLoss[row], minL);
        float z = __fmul_rn(-20.0f, l);
        float ez = expf(z);
        float sg = __fdiv_rn(ez, __fadd_rn(1.0f, ez));
        float wf = (__fmul_rn(2.0f, sg) > 0.5f) ? 1.0f : 0.0f;
        wsh[n] = wf;
        outW[row] = wf;
    }
    __syncthreads();

    // phase 3: Procrustes reductions (double, 16 waves)
    const float* xs = srcP + (size_t)b * 3 * NN;
    const float* ts = tgtP + (size_t)b * 3 * NN;
    double acc7[7] = {0, 0, 0, 0, 0, 0, 0};
    for (int n = tid; n < NN; n += 1024) {
        if (wsh[n] != 0.0f) {
            acc7[0] += 1.0;
            acc7[1] += (double)xs[n];
            acc7[2] += (double)xs[NN + n];
            acc7[3] += (double)xs[2 * NN + n];
            int m = csh[n];
            acc7[4] += (double)ts[m];
            acc7[5] += (double)ts[NN + m];
            acc7[6] += (double)ts[2 * NN + m];
        }
    }
#pragma unroll
    for (int q = 0; q < 7; q++) {
        double r = wave_red_sum_d(acc7[q]);
        if (lane == 0) sd[w][q] = r;
    }
    __syncthreads();
    double tot7[7];
#pragma unroll
    for (int q = 0; q < 7; q++) {
        double s2 = 0;
#pragma unroll
        for (int w2 = 0; w2 < 16; w2++) s2 += sd[w2][q];
        tot7[q] = s2;
    }
    __syncthreads();

    double W1e = tot7[0] + 1e-7;
    double mux0 = tot7[1] / W1e, mux1 = tot7[2] / W1e, mux2 = tot7[3] / W1e;
    double muy0 = tot7[4] / W1e, muy1 = tot7[5] / W1e, muy2 = tot7[6] / W1e;

    double s[9] = {0, 0, 0, 0, 0, 0, 0, 0, 0};
    for (int n = tid; n < NN; n += 1024) {
        if (wsh[n] != 0.0f) {
            double dx0 = (double)xs[n] - mux0;
            double dx1 = (double)xs[NN + n] - mux1;
            double dx2 = (double)xs[2 * NN + n] - mux2;
            int m = csh[n];
            double dy0 = (double)ts[m] - muy0;
            double dy1 = (double)ts[NN + m] - muy1;
            double dy2 = (double)ts[2 * NN + m] - muy2;
            s[0] += dy0 * dx0; s[1] += dy0 * dx1; s[2] += dy0 * dx2;
            s[3] += dy1 * dx0; s[4] += dy1 * dx1; s[5] += dy1 * dx2;
            s[6] += dy2 * dx0; s[7] += dy2 * dx1; s[8] += dy2 * dx2;
        }
    }
#pragma unroll
    for (int q = 0; q < 9; q++) {
        double r = wave_red_sum_d(s[q]);
        if (lane == 0) sd[w][q] = r;
    }
    __syncthreads();
    if (tid < 9) {
        double s2 = 0;
#pragma unroll
        for (int w2 = 0; w2 < 16; w2++) s2 += sd[w2][tid];
        sxySh[tid] = s2 / W1e;
    }
    __syncthreads();

    // phase 4: one thread does the 3x3 Jacobi SVD -> R, T
    if (tid == 0) {
        double Bm2[3][3], V[3][3];
        for (int r = 0; r < 3; r++)
            for (int c2 = 0; c2 < 3; c2++) {
                Bm2[r][c2] = sxySh[r * 3 + c2];
                V[r][c2] = (r == c2) ? 1.0 : 0.0;
            }
        double nrm2 = 0;
        for (int r = 0; r < 3; r++)
            for (int c2 = 0; c2 < 3; c2++) nrm2 += Bm2[r][c2] * Bm2[r][c2];

        for (int sweep = 0; sweep < 60; sweep++) {
            double off = 0;
            for (int p = 0; p < 2; p++) {
                for (int q = p + 1; q < 3; q++) {
                    double al = 0, be = 0, ga = 0;
                    for (int i = 0; i < 3; i++) {
                        al += Bm2[i][p] * Bm2[i][p];
                        be += Bm2[i][q] * Bm2[i][q];
                        ga += Bm2[i][p] * Bm2[i][q];
                    }
                    off += ga * ga;
                    if (fabs(ga) > 1e-300) {
                        double ze = (be - al) / (2.0 * ga);
                        double tt = copysign(1.0, ze) / (fabs(ze) + sqrt(1.0 + ze * ze));
                        double c = 1.0 / sqrt(1.0 + tt * tt), sn = c * tt;
                        for (int i = 0; i < 3; i++) {
                            double bp = Bm2[i][p], bq = Bm2[i][q];
                            Bm2[i][p] = c * bp - sn * bq;
                            Bm2[i][q] = sn * bp + c * bq;
                            double vp = V[i][p], vq = V[i][q];
                            V[i][p] = c * vp - sn * vq;
                            V[i][q] = sn * vp + c * vq;
                        }
                    }
                }
            }
            if (off <= 1e-30 * nrm2 * nrm2) break;
        }
        double sig[3];
        for (int j = 0; j < 3; j++) {
            double ss = 0;
            for (int i = 0; i < 3; i++) ss += Bm2[i][j] * Bm2[i][j];
            sig[j] = sqrt(ss);
        }
        for (int a = 0; a < 2; a++)
            for (int j = 0; j < 2 - a; j++)
                if (sig[j] < sig[j + 1]) {
                    double t2 = sig[j]; sig[j] = sig[j + 1]; sig[j + 1] = t2;
                    for (int i = 0; i < 3; i++) {
                        double tb = Bm2[i][j]; Bm2[i][j] = Bm2[i][j + 1]; Bm2[i][j + 1] = tb;
                        double tv = V[i][j]; V[i][j] = V[i][j + 1]; V[i][j + 1] = tv;
                    }
                }
        double U[3][3];
        for (int j = 0; j < 3; j++) {
            double inv = (sig[j] > 1e-150) ? 1.0 / sig[j] : 0.0;
            for (int i = 0; i < 3; i++) U[i][j] = Bm2[i][j] * inv;
        }
        if (sig[2] <= 1e-10 * (sig[0] + 1e-300)) {
            double u0 = U[1][0] * U[2][1] - U[2][0] * U[1][1];
            double u1 = U[2][0] * U[0][1] - U[0][0] * U[2][1];
            double u2 = U[0][0] * U[1][1] - U[1][0] * U[0][1];
            double nr = sqrt(u0 * u0 + u1 * u1 + u2 * u2);
            if (nr > 1e-150) { U[0][2] = u0 / nr; U[1][2] = u1 / nr; U[2][2] = u2 / nr; }
        }
        double dU = det3(U), dV = det3(V);
        double s3 = (dU * dV >= 0.0) ? 1.0 : -1.0;
        double R[3][3];
        for (int i = 0; i < 3; i++)
            for (int j = 0; j < 3; j++)
                R[i][j] = U[i][0] * V[j][0] + U[i][1] * V[j][1] + s3 * U[i][2] * V[j][2];
        double mux[3] = {mux0, mux1, mux2};
        double muy[3] = {muy0, muy1, muy2};
        for (int i = 0; i < 3; i++) {
            for (int j = 0; j < 3; j++) outR[b * 9 + i * 3 + j] = (float)R[i][j];
            double t2 = muy[i] - (R[i][0] * mux[0] + R[i][1] * mux[1] + R[i][2] * mux[2]);
            outT[b * 3 + i] = (float)t2;
        }
    }
}

// ---------------------------------------------------------------------------
// host launcher
// ---------------------------------------------------------------------------
extern "C" void kernel_launch(void* const* d_in, const int* in_sizes, int n_in,
                              void* d_out, int out_size, void* d_ws, size_t ws_size,
                              hipStream_t stream) {
    const float* srcE = (const float*)d_in[0];
    const float* tgtE = (const float*)d_in[1];
    const float* srcP = (const float*)d_in[2];
    const float* tgtP = (const float*)d_in[3];
    float* out = (float*)d_out;  // R[36] T[12] corres[8192] weight[8192]

    char* w = (char*)d_ws;
    size_t off = 0;
    auto alloc = [&](size_t bytes) -> void* {
        void* p = w + off;
        off = (off + bytes + 255) & ~(size_t)255;
        return p;
    };
    float* corrTgt = (float*)alloc((size_t)NBATCH * NN * 3 * 4);
    int* corres = (int*)alloc((size_t)NBATCH * NN * 4);
    int* flags = (int*)alloc((size_t)NBATCH * NN * 4);
    unsigned long long* keys = (unsigned long long*)alloc((size_t)NBATCH * NN * 8);
    int* list = (int*)alloc((size_t)NBATCH * NN * 32 * 4);  // worst-case all tiles
    int* count = (int*)alloc(256);
    float* pointLoss = (float*)alloc((size_t)NBATCH * NN * 4);
    size_t planeShorts = (size_t)NBATCH * 16 * NN * 32;  // 8.4 MB per plane
    short* Ah = (short*)alloc(planeShorts * 2);
    short* Bh = (short*)alloc(planeShorts * 2);
    float* part = (float*)alloc((size_t)NBATCH * NN * 32 * 4 * 4);  // 4.2 MB

    prep_planes<<<dim3(512, NBATCH, 2), 256, 0, stream>>>(srcE, tgtE, Ah, Bh, count);
    gemm_fused<<<dim3(NN / 128, NN / 128, NBATCH), 256, 0, stream>>>(Ah, Bh, part);
    combine_rows<<<dim3(NN / 4, NBATCH), 256, 0, stream>>>(part, tgtP, corres, flags, list,
                                                           count, keys, corrTgt);
    gfm_kernel<<<dim3(NN / 8, NBATCH), 512, 0, stream>>>(srcP, corrTgt, pointLoss);
    refine_tiles<<<dim3(2048), 256, 0, stream>>>(srcE, tgtE, list, count, keys);
    fused_finish<<<NBATCH, 1024, 0, stream>>>(pointLoss, flags, keys, corres, srcP, tgtP,
                                              out, out + 36, out + 48, out + 48 + NBATCH * NN);
}

// Round 17
// 129.440 us; speedup vs baseline: 1.1177x; 1.0176x over previous
//
#include <hip/hip_runtime.h>
#include <hip/hip_bf16.h>

#define NN 2048
#define DD 512
#define NBATCH 4
#define KNB 10
#define NPAIR 45

typedef __attribute__((ext_vector_type(8))) _Float16 f16x8;
typedef __attribute__((ext_vector_type(4))) float f32x4;

// ---------------------------------------------------------------------------
// helpers
// ---------------------------------------------------------------------------
__device__ __forceinline__ float tri_area(float p0x, float p0y, float p0z,
                                          float p1x, float p1y, float p1z,
                                          float p2x, float p2y, float p2z) {
    float e1x = __fsub_rn(p1x, p0x), e1y = __fsub_rn(p1y, p0y), e1z = __fsub_rn(p1z, p0z);
    float e2x = __fsub_rn(p2x, p0x), e2y = __fsub_rn(p2y, p0y), e2z = __fsub_rn(p2z, p0z);
    float c0 = __fsub_rn(__fmul_rn(e1y, e2z), __fmul_rn(e1z, e2y));
    float c1 = __fsub_rn(__fmul_rn(e1z, e2x), __fmul_rn(e1x, e2z));
    float c2 = __fsub_rn(__fmul_rn(e1x, e2y), __fmul_rn(e1y, e2x));
    float ss = __fadd_rn(__fadd_rn(__fmul_rn(c0, c0), __fmul_rn(c1, c1)), __fmul_rn(c2, c2));
    return __fmul_rn(0.5f, sqrtf(ss));
}

__device__ __forceinline__ double wave_red_sum_d(double v) {
#pragma unroll
    for (int st = 1; st < 64; st <<= 1) v += __shfl_xor(v, st, 64);
    return v;
}

// ---------------------------------------------------------------------------
// K0: prep_planes — f32 -> fp16 h plane, pre-tiled + pre-swizzled.
// Coalesced lane map: n = ng*64 + (t&63), gg = t>>6.  Also zeroes `count`.
// ---------------------------------------------------------------------------
__global__ __launch_bounds__(256) void prep_planes(const float* __restrict__ srcE,
                                                   const float* __restrict__ tgtE,
                                                   short* __restrict__ Ah,
                                                   short* __restrict__ Bh,
                                                   int* __restrict__ count) {
    int kt = blockIdx.x & 15, ng = blockIdx.x >> 4;
    int b = blockIdx.y, mat = blockIdx.z;
    int t = threadIdx.x;
    if (blockIdx.x == 0 && b == 0 && mat == 0 && t == 0) count[0] = 0;
    int nloc = t & 63, gg = t >> 6;
    int n = ng * 64 + nloc;
    int d0 = kt * 32 + gg * 8;
    const float* src = (mat ? tgtE : srcE) + (size_t)b * DD * NN;
    short* PH = mat ? Bh : Ah;

    float x[8];
#pragma unroll
    for (int j = 0; j < 8; j++) x[j] = src[(size_t)(d0 + j) * NN + n];
    unsigned h4[4];
#pragma unroll
    for (int p = 0; p < 4; p++) {
        _Float16 h0 = (_Float16)x[2 * p], h1 = (_Float16)x[2 * p + 1];  // RNE
        h4[p] = (unsigned)__builtin_bit_cast(unsigned short, h0) |
                ((unsigned)__builtin_bit_cast(unsigned short, h1) << 16);
    }
    size_t o = ((size_t)(b * 16 + kt) * NN + n) * 32 + ((gg ^ ((n >> 1) & 3)) << 3);
    *(uint4*)&PH[o] = (uint4){h4[0], h4[1], h4[2], h4[3]};
}

// ---------------------------------------------------------------------------
// K1: depth-2 pipelined MFMA GEMM (fp16 1-product): ring of 3 LDS buffers,
// counted vmcnt(4) + raw s_barrier (next tile's loads stay in flight across
// the barrier) + top-2/argmax epilogue.
// ---------------------------------------------------------------------------
__global__ __launch_bounds__(256) void gemm_fused(const short* __restrict__ Ah,
                                                  const short* __restrict__ Bh,
                                                  float* __restrict__ part) {
    int b = blockIdx.z;
    int id = blockIdx.y * 16 + blockIdx.x;
    int swz = (id & 7) * 32 + (id >> 3);  // XCD-bijective (256 % 8 == 0)
    int bx = swz & 15, by = swz >> 4;
    int n0 = by * 128, m0 = bx * 128;

    __shared__ short LDS[3][2][4096];  // ring of 3 x [plane: Ah Bh] = 48 KB

    int t = threadIdx.x, w = t >> 6, lane = t & 63;
    int wr = w >> 1, wc = w & 1;
    int fr = lane & 15, kq = lane >> 4;

    const short* gpl[2] = {Ah, Bh};

    f32x4 acc[4][4];
#pragma unroll
    for (int i = 0; i < 4; i++)
#pragma unroll
        for (int j = 0; j < 4; j++) acc[i][j] = (f32x4){0.f, 0.f, 0.f, 0.f};

    auto STAGE = [&](int buf, int kt) {
#pragma unroll
        for (int q = 0; q < 4; q++) {
            int p = q >> 1, h = q & 1;
            int rb = (p == 0) ? n0 : m0;
            const short* g = gpl[p] + ((size_t)(b * 16 + kt) * NN + rb) * 32 +
                             h * 2048 + w * 512 + lane * 8;
            __builtin_amdgcn_global_load_lds(
                (const __attribute__((address_space(1))) void*)g,
                (__attribute__((address_space(3))) void*)&LDS[buf][p][h * 2048 + w * 512],
                16, 0, 0);
        }
    };

    STAGE(0, 0);
    STAGE(1, 1);  // 8 loads in flight
    for (int kt = 0; kt < 16; kt++) {
        // wait for THIS tile's 4 loads only; next tile's 4 stay in flight
        if (kt < 15) {
            asm volatile("s_waitcnt vmcnt(4)" ::: "memory");
        } else {
            asm volatile("s_waitcnt vmcnt(0)" ::: "memory");
        }
        __builtin_amdgcn_s_barrier();      // raw barrier: no vmcnt(0) drain
        __builtin_amdgcn_sched_barrier(0); // pin ds_reads after the waitcnt

        int cur = kt % 3;
        f16x8 ah[4], bh[4];
#pragma unroll
        for (int i = 0; i < 4; i++) {
            int rA = wr * 64 + i * 16 + fr;
            int offA = rA * 32 + ((kq ^ ((rA >> 1) & 3)) << 3);
            ah[i] = *(const f16x8*)&LDS[cur][0][offA];
            int rB = wc * 64 + i * 16 + fr;
            int offB = rB * 32 + ((kq ^ ((rB >> 1) & 3)) << 3);
            bh[i] = *(const f16x8*)&LDS[cur][1][offB];
        }
#pragma unroll
        for (int i = 0; i < 4; i++)
#pragma unroll
            for (int j = 0; j < 4; j++)
                acc[i][j] = __builtin_amdgcn_mfma_f32_16x16x32_f16(ah[i], bh[j],
                                                                   acc[i][j], 0, 0, 0);
        // ring write target (kt+2)%3 == (kt-1)%3: all waves finished reading it
        // before this iteration's barrier
        if (kt < 14) STAGE((kt + 2) % 3, kt + 2);
        __builtin_amdgcn_s_barrier();  // readers done before next overwrite
    }

    // ---- top-2/argmax epilogue ----
    int t32 = bx * 2 + wc;
#pragma unroll
    for (int i = 0; i < 4; i++) {
#pragma unroll
        for (int rg = 0; rg < 4; rg++) {
            int row = n0 + wr * 64 + i * 16 + kq * 4 + rg;
            float m1 = -3.4e38f, m2 = -3.4e38f;
            int i1 = 0x7fffffff;
#pragma unroll
            for (int j = 0; j < 4; j++) {
                float vv = __fmul_rn(10000.0f, __fdiv_rn(acc[i][j][rg], 22.627416997969522f));
                int col = m0 + wc * 64 + j * 16 + fr;
                if (vv > m1) { m2 = m1; m1 = vv; i1 = col; }
                else if (vv > m2) m2 = vv;
            }
#pragma unroll
            for (int st = 1; st < 16; st <<= 1) {
                float om1 = __shfl_xor(m1, st, 64);
                float om2 = __shfl_xor(m2, st, 64);
                int oi1 = __shfl_xor(i1, st, 64);
                if (om1 > m1 || (om1 == m1 && oi1 < i1)) {
                    m2 = fmaxf(m1, om2); m1 = om1; i1 = oi1;
                } else {
                    m2 = fmaxf(om1, m2);
                }
            }
            if (fr == 0) {
                size_t o = ((size_t)(b * NN + row) * 32 + t32) * 4;
                *(float4*)&part[o] = (float4){m1, m2, (float)i1, 0.f};
            }
        }
    }
}

// ---------------------------------------------------------------------------
// K2: merge partials -> corres0, flags; push PRUNED (row,tile) refine items;
// gather corrTgt = tgt[:, corres0]
// ---------------------------------------------------------------------------
__global__ __launch_bounds__(256) void combine_rows(const float* __restrict__ part,
                                                    const float* __restrict__ tgtP,
                                                    int* __restrict__ corres,
                                                    int* __restrict__ flags,
                                                    int* __restrict__ list,
                                                    int* __restrict__ count,
                                                    unsigned long long* __restrict__ keys,
                                                    float* __restrict__ corrTgt) {
    int b = blockIdx.y;
    int w = threadIdx.x >> 6, lane = threadIdx.x & 63;
    int n = blockIdx.x * 4 + w;
    int row = b * NN + n;
    float m1 = -3.4e38f, m2 = -3.4e38f;
    int i1 = 0x7fffffff;
    if (lane < 32) {
        float4 p1 = *(const float4*)&part[((size_t)row * 32 + lane) * 4];
        m1 = p1.x; m2 = p1.y; i1 = (int)p1.z;
    }
    float tm1 = m1;  // per-lane tile max, preserved through the reduction
#pragma unroll
    for (int st = 1; st < 64; st <<= 1) {
        float om1 = __shfl_xor(m1, st, 64);
        float om2 = __shfl_xor(m2, st, 64);
        int oi1 = __shfl_xor(i1, st, 64);
        if (om1 > m1 || (om1 == m1 && oi1 < i1)) {
            m2 = fmaxf(m1, om2); m1 = om1; i1 = oi1;
        } else {
            m2 = fmaxf(om1, m2);
        }
    }
    // fp16 1-product error sigma ~4.7 sv per score; flag if gap < 34 (~5 sigma)
    int fl = (__fsub_rn(m1, m2) < 34.0f) ? 1 : 0;
    // tile-prune: margin must cover |err(c1)|+|err(c*)| (sigma~6.6) -> 44
    bool pred = fl && (lane < 32) && (tm1 >= __fsub_rn(m1, 44.0f));
    unsigned long long mask = __ballot(pred);
    int base = 0;
    if (fl) {
        if (lane == 0) {
            flags[row] = 1;
            keys[row] = 0ull;  // refine runs later in stream order
            base = atomicAdd(count, __popcll(mask));
        }
        base = __shfl(base, 0, 64);
        if (pred) {
            int rank = __popcll(mask & ((1ull << lane) - 1ull));
            list[base + rank] = (row << 5) | lane;  // (row, tile)
        }
    } else if (lane == 0) {
        flags[row] = 0;
    }
    if (lane == 0) {
        corres[row] = i1;
        const float* tb = tgtP + (size_t)b * 3 * NN;
        corrTgt[(size_t)row * 3 + 0] = tb[i1];
        corrTgt[(size_t)row * 3 + 1] = tb[NN + i1];
        corrTgt[(size_t)row * 3 + 2] = tb[2 * NN + i1];
    }
}

// ---------------------------------------------------------------------------
// K2b: tile-pruned exact-f32 argmax refine. Item = (row, 64-col tile);
// 256 threads = 64 cols x 4-way K-split; A-col in LDS; atomicMax packed key.
// ---------------------------------------------------------------------------
__global__ __launch_bounds__(256) void refine_tiles(const float* __restrict__ A,
                                                    const float* __restrict__ Bm,
                                                    const int* __restrict__ list,
                                                    const int* __restrict__ count,
                                                    unsigned long long* __restrict__ keys) {
    int tid = threadIdx.x;
    int c = tid & 63, ks = tid >> 6;
    __shared__ float Acol[DD];
    __shared__ float partial[4][64];
    int nitems = count[0];
    for (int item = blockIdx.x; item < nitems; item += 2048) {
        int code = list[item];
        int row = code >> 5, tile = code & 31;
        int b = row / NN, n = row % NN;
        const float* Ab = A + (size_t)b * DD * NN;
        const float* Bb = Bm + (size_t)b * DD * NN;
        Acol[tid] = Ab[(size_t)tid * NN + n];
        Acol[tid + 256] = Ab[(size_t)(tid + 256) * NN + n];
        __syncthreads();
        int m = tile * 64 + c;
        float acc = 0.f;
        int dbase = ks * 128;
        for (int d = 0; d < 128; d++)
            acc = fmaf(Acol[dbase + d], Bb[(size_t)(dbase + d) * NN + m], acc);
        partial[ks][c] = acc;
        __syncthreads();
        if (tid < 64) {  // one wave finishes: sum K-splits, pack key, reduce
            float tot = __fadd_rn(__fadd_rn(partial[0][c], partial[1][c]),
                                  __fadd_rn(partial[2][c], partial[3][c]));
            float sc = __fmul_rn(10000.0f, __fdiv_rn(tot, 22.627416997969522f));
            unsigned u = __float_as_uint(sc);
            u = (u & 0x80000000u) ? ~u : (u | 0x80000000u);  // order-preserving
            unsigned long long key =
                ((unsigned long long)u << 32) | (unsigned)(~(unsigned)m);
#pragma unroll
            for (int st = 1; st < 64; st <<= 1) {
                unsigned long long ok = __shfl_xor((long long)key, st, 64);
                if (ok > key) key = ok;
            }
            if (c == 0) atomicMax(&keys[row], key);
        }
        __syncthreads();
    }
}

// ---------------------------------------------------------------------------
// K3: GFM — 512 threads, 8 points/block (1 per wave).  AoS float4 cloud in
// LDS (b128 loads) + packed u32 selection keys.  (round-14 verified winner)
// ---------------------------------------------------------------------------
__global__ __launch_bounds__(512) void gfm_kernel(const float* __restrict__ srcP,
                                                  const float* __restrict__ corrTgt,
                                                  float* __restrict__ pointLoss) {
    int b = blockIdx.y, tid = threadIdx.x;
    int w = tid >> 6, lane = tid & 63;
    int n = blockIdx.x * 8 + w;
    __shared__ float4 XP[NN];  // {x, y, z, sq} = 32 KB
    __shared__ int nbl[8][KNB];
    __shared__ float ptb[8][KNB][3];
    __shared__ float la[8][NPAIR], rg[8][NPAIR], srt[8][NPAIR];
    const float* xs = srcP + (size_t)b * 3 * NN;

    for (int i = tid; i < NN / 4; i += 512) {
        float4 u0 = ((const float4*)xs)[i];
        float4 u1 = ((const float4*)(xs + NN))[i];
        float4 u2 = ((const float4*)(xs + 2 * NN))[i];
        float4 q;
        q.x = __fadd_rn(__fadd_rn(__fmul_rn(u0.x, u0.x), __fmul_rn(u1.x, u1.x)), __fmul_rn(u2.x, u2.x));
        q.y = __fadd_rn(__fadd_rn(__fmul_rn(u0.y, u0.y), __fmul_rn(u1.y, u1.y)), __fmul_rn(u2.y, u2.y));
        q.z = __fadd_rn(__fadd_rn(__fmul_rn(u0.z, u0.z), __fmul_rn(u1.z, u1.z)), __fmul_rn(u2.z, u2.z));
        q.w = __fadd_rn(__fadd_rn(__fmul_rn(u0.w, u0.w), __fmul_rn(u1.w, u1.w)), __fmul_rn(u2.w, u2.w));
        XP[4 * i + 0] = (float4){u0.x, u1.x, u2.x, q.x};
        XP[4 * i + 1] = (float4){u0.y, u1.y, u2.y, q.y};
        XP[4 * i + 2] = (float4){u0.z, u1.z, u2.z, q.z};
        XP[4 * i + 3] = (float4){u0.w, u1.w, u2.w, q.w};
    }
    __syncthreads();

    float4 av = XP[n];
    float a0 = av.x, a1 = av.y, a2 = av.z, sqa = av.w;
    unsigned key[32];
#pragma unroll
    for (int r = 0; r < 32; r++) {
        int m = lane + 64 * r;
        float4 p = XP[m];
        float dot = __fadd_rn(__fadd_rn(__fmul_rn(a0, p.x), __fmul_rn(a1, p.y)),
                              __fmul_rn(a2, p.z));
        float d2 = __fsub_rn(__fadd_rn(sqa, p.w), __fmul_rn(2.0f, dot));
        d2 = fmaxf(d2, 0.0f);
        key[r] = (__float_as_uint(d2) & 0xFFFFF800u) | (unsigned)m;
    }
    unsigned removed = 0;
#pragma unroll
    for (int it = 0; it < KNB; it++) {
        unsigned best = 0xFFFFFFFFu;
#pragma unroll
        for (int r = 0; r < 32; r++) {
            unsigned kk = ((removed >> r) & 1u) ? 0xFFFFFFFFu : key[r];
            best = min(best, kk);
        }
#pragma unroll
        for (int st = 1; st < 64; st <<= 1) {
            unsigned ob = __shfl_xor((int)best, st, 64);
            best = min(best, ob);
        }
        int m = (int)(best & 2047u);
        if (lane == 0) nbl[w][it] = m;
        removed |= ((m & 63) == lane) ? (1u << (m >> 6)) : 0u;
    }
    __builtin_amdgcn_wave_barrier();
    if (lane < KNB) {
        int ia = nbl[w][lane];
        const float* ct = corrTgt + ((size_t)b * NN + ia) * 3;
        ptb[w][lane][0] = ct[0];
        ptb[w][lane][1] = ct[1];
        ptb[w][lane][2] = ct[2];
    }
    __builtin_amdgcn_wave_barrier();
    const float* ctn = corrTgt + ((size_t)b * NN + n) * 3;
    float t0 = ctn[0], t1 = ctn[1], t2 = ctn[2];
    if (lane < NPAIR) {
        int k = lane, ja = 0, cnt = 9;
        while (k >= cnt) { k -= cnt; ja++; cnt--; }
        int jb = ja + 1 + k;
        int ia = nbl[w][ja], ib = nbl[w][jb];
        float4 pa = XP[ia], pb = XP[ib];
        float area_s = tri_area(a0, a1, a2, pa.x, pa.y, pa.z, pb.x, pb.y, pb.z);
        float area_t = tri_area(t0, t1, t2, ptb[w][ja][0], ptb[w][ja][1], ptb[w][ja][2],
                                ptb[w][jb][0], ptb[w][jb][1], ptb[w][jb][2]);
        const float EPSF = 1e-6f;
        float ee = __fmul_rn(EPSF, EPSF);
        float lt2 = __fadd_rn(area_t, EPSF);
        float da = __fsub_rn(area_s, lt2);
        float sa = __fadd_rn(area_s, lt2);
        float num = __fadd_rn(__fadd_rn(ee, ee), __fmul_rn(da, da));
        float den = __fadd_rn(__fadd_rn(ee, ee), __fmul_rn(sa, sa));
        la[w][lane] = __fdiv_rn(num, den);
        rg[w][lane] = sqrtf(num);
    }
    __builtin_amdgcn_wave_barrier();
    if (lane < NPAIR) {
        float x = la[w][lane];
        int rk = 0;
        for (int j = 0; j < NPAIR; j++) {
            float y = la[w][j];
            rk += (y < x || (y == x && j < lane)) ? 1 : 0;
        }
        srt[w][rk] = x;
    }
    __builtin_amdgcn_wave_barrier();
    float l2v = 0.f;
    if (lane < NPAIR) l2v = __fadd_rn(srt[w][lane], __fmul_rn(0.1f, rg[w][lane]));
    __builtin_amdgcn_wave_barrier();
    if (lane < NPAIR) la[w][lane] = l2v;
    __builtin_amdgcn_wave_barrier();
    if (lane < NPAIR) {
        float x = la[w][lane];
        int rk = 0;
        for (int j = 0; j < NPAIR; j++) {
            float y = la[w][j];
            rk += (y < x || (y == x && j < lane)) ? 1 : 0;
        }
        srt[w][rk] = x;
    }
    __builtin_amdgcn_wave_barrier();
    float med = srt[w][22];
    float thr = __fmul_rn(3.0f, med);
    float term = 0.f;
    if (lane < KNB) {
        float vv = la[w][lane];
        if (vv > thr) vv = 0.f;
        term = sqrtf(__fadd_rn(vv, 1e-6f));
    }
#pragma unroll
    for (int st = 1; st < 64; st <<= 1) term += __shfl_xor(term, st, 64);
    if (lane == 0) pointLoss[b * NN + n] = __fdiv_rn(term, 10.0f);
}

// ---------------------------------------------------------------------------
// K4: fused finish — 1024 threads/batch: refined corres, min, weight,
// Procrustes reductions, 3x3 Jacobi SVD
// ---------------------------------------------------------------------------
__device__ double det3(const double M[3][3]) {
    return M[0][0] * (M[1][1] * M[2][2] - M[1][2] * M[2][1]) -
           M[0][1] * (M[1][0] * M[2][2] - M[1][2] * M[2][0]) +
           M[0][2] * (M[1][0] * M[2][1] - M[1][1] * M[2][0]);
}

__global__ __launch_bounds__(1024) void fused_finish(const float* __restrict__ pointLoss,
                                                     const int* __restrict__ flags,
                                                     const unsigned long long* __restrict__ keys,
                                                     const int* __restrict__ corresIn,
                                                     const float* __restrict__ srcP,
                                                     const float* __restrict__ tgtP,
                                                     float* __restrict__ outR,
                                                     float* __restrict__ outT,
                                                     float* __restrict__ outC,
                                                     float* __restrict__ outW) {
    int b = blockIdx.x, tid = threadIdx.x;
    int w = tid >> 6, lane = tid & 63;
    __shared__ int csh[NN];
    __shared__ float wsh[NN];
    __shared__ float fred[1024];
    __shared__ double sd[16][9];
    __shared__ double sxySh[9];

    // phase 1: final corres (apply refined keys) + min(pointLoss)
    float mn = 3.4e38f;
    for (int n = tid; n < NN; n += 1024) {
        int row = b * NN + n;
        int ci = corresIn[row];
        if (flags[row]) ci = (int)(~(unsigned)(keys[row] & 0xFFFFFFFFull));
        csh[n] = ci;
        outC[row] = (float)ci;
        mn = fminf(mn, pointLoss[row]);
    }
    fred[tid] = mn;
    __syncthreads();
    for (int st = 512; st > 0; st >>= 1) {
        if (tid < st) fred[tid] = fminf(fred[tid], fred[tid + st]);
        __syncthreads();
    }
    float minL = fred[0];
    __syncthreads();

    // phase 2: weight
    for (int n = tid; n < NN; n += 1024) {
        int row = b * NN + n;
        float l = __fsub_rn(pointLoss[row], minL);
        float z = __fmul_rn(-20.0f, l);
        float ez = expf(z);
        float sg = __fdiv_rn(ez, __fadd_rn(1.0f, ez));
        float wf = (__fmul_rn(2.0f, sg) > 0.5f) ? 1.0f : 0.0f;
        wsh[n] = wf;
        outW[row] = wf;
    }
    __syncthreads();

    // phase 3: Procrustes reductions (double, 16 waves)
    const float* xs = srcP + (size_t)b * 3 * NN;
    const float* ts = tgtP + (size_t)b * 3 * NN;
    double acc7[7] = {0, 0, 0, 0, 0, 0, 0};
    for (int n = tid; n < NN; n += 1024) {
        if (wsh[n] != 0.0f) {
            acc7[0] += 1.0;
            acc7[1] += (double)xs[n];
            acc7[2] += (double)xs[NN + n];
            acc7[3] += (double)xs[2 * NN + n];
            int m = csh[n];
            acc7[4] += (double)ts[m];
            acc7[5] += (double)ts[NN + m];
            acc7[6] += (double)ts[2 * NN + m];
        }
    }
#pragma unroll
    for (int q = 0; q < 7; q++) {
        double r = wave_red_sum_d(acc7[q]);
        if (lane == 0) sd[w][q] = r;
    }
    __syncthreads();
    double tot7[7];
#pragma unroll
    for (int q = 0; q < 7; q++) {
        double s2 = 0;
#pragma unroll
        for (int w2 = 0; w2 < 16; w2++) s2 += sd[w2][q];
        tot7[q] = s2;
    }
    __syncthreads();

    double W1e = tot7[0] + 1e-7;
    double mux0 = tot7[1] / W1e, mux1 = tot7[2] / W1e, mux2 = tot7[3] / W1e;
    double muy0 = tot7[4] / W1e, muy1 = tot7[5] / W1e, muy2 = tot7[6] / W1e;

    double s[9] = {0, 0, 0, 0, 0, 0, 0, 0, 0};
    for (int n = tid; n < NN; n += 1024) {
        if (wsh[n] != 0.0f) {
            double dx0 = (double)xs[n] - mux0;
            double dx1 = (double)xs[NN + n] - mux1;
            double dx2 = (double)xs[2 * NN + n] - mux2;
            int m = csh[n];
            double dy0 = (double)ts[m] - muy0;
            double dy1 = (double)ts[NN + m] - muy1;
            double dy2 = (double)ts[2 * NN + m] - muy2;
            s[0] += dy0 * dx0; s[1] += dy0 * dx1; s[2] += dy0 * dx2;
            s[3] += dy1 * dx0; s[4] += dy1 * dx1; s[5] += dy1 * dx2;
            s[6] += dy2 * dx0; s[7] += dy2 * dx1; s[8] += dy2 * dx2;
        }
    }
#pragma unroll
    for (int q = 0; q < 9; q++) {
        double r = wave_red_sum_d(s[q]);
        if (lane == 0) sd[w][q] = r;
    }
    __syncthreads();
    if (tid < 9) {
        double s2 = 0;
#pragma unroll
        for (int w2 = 0; w2 < 16; w2++) s2 += sd[w2][tid];
        sxySh[tid] = s2 / W1e;
    }
    __syncthreads();

    // phase 4: one thread does the 3x3 Jacobi SVD -> R, T
    if (tid == 0) {
        double Bm2[3][3], V[3][3];
        for (int r = 0; r < 3; r++)
            for (int c2 = 0; c2 < 3; c2++) {
                Bm2[r][c2] = sxySh[r * 3 + c2];
                V[r][c2] = (r == c2) ? 1.0 : 0.0;
            }
        double nrm2 = 0;
        for (int r = 0; r < 3; r++)
            for (int c2 = 0; c2 < 3; c2++) nrm2 += Bm2[r][c2] * Bm2[r][c2];

        for (int sweep = 0; sweep < 60; sweep++) {
            double off = 0;
            for (int p = 0; p < 2; p++) {
                for (int q = p + 1; q < 3; q++) {
                    double al = 0, be = 0, ga = 0;
                    for (int i = 0; i < 3; i++) {
                        al += Bm2[i][p] * Bm2[i][p];
                        be += Bm2[i][q] * Bm2[i][q];
                        ga += Bm2[i][p] * Bm2[i][q];
                    }
                    off += ga * ga;
                    if (fabs(ga) > 1e-300) {
                        double ze = (be - al) / (2.0 * ga);
                        double tt = copysign(1.0, ze) / (fabs(ze) + sqrt(1.0 + ze * ze));
                        double c = 1.0 / sqrt(1.0 + tt * tt), sn = c * tt;
                        for (int i = 0; i < 3; i++) {
                            double bp = Bm2[i][p], bq = Bm2[i][q];
                            Bm2[i][p] = c * bp - sn * bq;
                            Bm2[i][q] = sn * bp + c * bq;
                            double vp = V[i][p], vq = V[i][q];
                            V[i][p] = c * vp - sn * vq;
                            V[i][q] = sn * vp + c * vq;
                        }
                    }
                }
            }
            if (off <= 1e-30 * nrm2 * nrm2) break;
        }
        double sig[3];
        for (int j = 0; j < 3; j++) {
            double ss = 0;
            for (int i = 0; i < 3; i++) ss += Bm2[i][j] * Bm2[i][j];
            sig[j] = sqrt(ss);
        }
        for (int a = 0; a < 2; a++)
            for (int j = 0; j < 2 - a; j++)
                if (sig[j] < sig[j + 1]) {
                    double t2 = sig[j]; sig[j] = sig[j + 1]; sig[j + 1] = t2;
                    for (int i = 0; i < 3; i++) {
                        double tb = Bm2[i][j]; Bm2[i][j] = Bm2[i][j + 1]; Bm2[i][j + 1] = tb;
                        double tv = V[i][j]; V[i][j] = V[i][j + 1]; V[i][j + 1] = tv;
                    }
                }
        double U[3][3];
        for (int j = 0; j < 3; j++) {
            double inv = (sig[j] > 1e-150) ? 1.0 / sig[j] : 0.0;
            for (int i = 0; i < 3; i++) U[i][j] = Bm2[i][j] * inv;
        }
        if (sig[2] <= 1e-10 * (sig[0] + 1e-300)) {
            double u0 = U[1][0] * U[2][1] - U[2][0] * U[1][1];
            double u1 = U[2][0] * U[0][1] - U[0][0] * U[2][1];
            double u2 = U[0][0] * U[1][1] - U[1][0] * U[0][1];
            double nr = sqrt(u0 * u0 + u1 * u1 + u2 * u2);
            if (nr > 1e-150) { U[0][2] = u0 / nr; U[1][2] = u1 / nr; U[2][2] = u2 / nr; }
        }
        double dU = det3(U), dV = det3(V);
        double s3 = (dU * dV >= 0.0) ? 1.0 : -1.0;
        double R[3][3];
        for (int i = 0; i < 3; i++)
            for (int j = 0; j < 3; j++)
                R[i][j] = U[i][0] * V[j][0] + U[i][1] * V[j][1] + s3 * U[i][2] * V[j][2];
        double mux[3] = {mux0, mux1, mux2};
        double muy[3] = {muy0, muy1, muy2};
        for (int i = 0; i < 3; i++) {
            for (int j = 0; j < 3; j++) outR[b * 9 + i * 3 + j] = (float)R[i][j];
            double t2 = muy[i] - (R[i][0] * mux[0] + R[i][1] * mux[1] + R[i][2] * mux[2]);
            outT[b * 3 + i] = (float)t2;
        }
    }
}

// ---------------------------------------------------------------------------
// host launcher
// ---------------------------------------------------------------------------
extern "C" void kernel_launch(void* const* d_in, const int* in_sizes, int n_in,
                              void* d_out, int out_size, void* d_ws, size_t ws_size,
                              hipStream_t stream) {
    const float* srcE = (const float*)d_in[0];
    const float* tgtE = (const float*)d_in[1];
    const float* srcP = (const float*)d_in[2];
    const float* tgtP = (const float*)d_in[3];
    float* out = (float*)d_out;  // R[36] T[12] corres[8192] weight[8192]

    char* w = (char*)d_ws;
    size_t off = 0;
    auto alloc = [&](size_t bytes) -> void* {
        void* p = w + off;
        off = (off + bytes + 255) & ~(size_t)255;
        return p;
    };
    float* corrTgt = (float*)alloc((size_t)NBATCH * NN * 3 * 4);
    int* corres = (int*)alloc((size_t)NBATCH * NN * 4);
    int* flags = (int*)alloc((size_t)NBATCH * NN * 4);
    unsigned long long* keys = (unsigned long long*)alloc((size_t)NBATCH * NN * 8);
    int* list = (int*)alloc((size_t)NBATCH * NN * 32 * 4);  // worst-case all tiles
    int* count = (int*)alloc(256);
    float* pointLoss = (float*)alloc((size_t)NBATCH * NN * 4);
    size_t planeShorts = (size_t)NBATCH * 16 * NN * 32;  // 8.4 MB per plane
    short* Ah = (short*)alloc(planeShorts * 2);
    short* Bh = (short*)alloc(planeShorts * 2);
    float* part = (float*)alloc((size_t)NBATCH * NN * 32 * 4 * 4);  // 4.2 MB

    prep_planes<<<dim3(512, NBATCH, 2), 256, 0, stream>>>(srcE, tgtE, Ah, Bh, count);
    gemm_fused<<<dim3(NN / 128, NN / 128, NBATCH), 256, 0, stream>>>(Ah, Bh, part);
    combine_rows<<<dim3(NN / 4, NBATCH), 256, 0, stream>>>(part, tgtP, corres, flags, list,
                                                           count, keys, corrTgt);
    gfm_kernel<<<dim3(NN / 8, NBATCH), 512, 0, stream>>>(srcP, corrTgt, pointLoss);
    refine_tiles<<<dim3(2048), 256, 0, stream>>>(srcE, tgtE, list, count, keys);
    fused_finish<<<NBATCH, 1024, 0, stream>>>(pointLoss, flags, keys, corres, srcP, tgtP,
                                              out, out + 36, out + 48, out + 48 + NBATCH * NN);
}

// Round 18
// 119.530 us; speedup vs baseline: 1.2104x; 1.0829x over previous
//
#include <hip/hip_runtime.h>
#include <hip/hip_bf16.h>

#define NN 2048
#define DD 512
#define NBATCH 4
#define KNB 10
#define NPAIR 45

typedef __attribute__((ext_vector_type(8))) _Float16 f16x8;
typedef __attribute__((ext_vector_type(4))) float f32x4;

// ---------------------------------------------------------------------------
// helpers
// ---------------------------------------------------------------------------
__device__ __forceinline__ float tri_area(float p0x, float p0y, float p0z,
                                          float p1x, float p1y, float p1z,
                                          float p2x, float p2y, float p2z) {
    float e1x = __fsub_rn(p1x, p0x), e1y = __fsub_rn(p1y, p0y), e1z = __fsub_rn(p1z, p0z);
    float e2x = __fsub_rn(p2x, p0x), e2y = __fsub_rn(p2y, p0y), e2z = __fsub_rn(p2z, p0z);
    float c0 = __fsub_rn(__fmul_rn(e1y, e2z), __fmul_rn(e1z, e2y));
    float c1 = __fsub_rn(__fmul_rn(e1z, e2x), __fmul_rn(e1x, e2z));
    float c2 = __fsub_rn(__fmul_rn(e1x, e2y), __fmul_rn(e1y, e2x));
    float ss = __fadd_rn(__fadd_rn(__fmul_rn(c0, c0), __fmul_rn(c1, c1)), __fmul_rn(c2, c2));
    return __fmul_rn(0.5f, sqrtf(ss));
}

__device__ __forceinline__ double wave_red_sum_d(double v) {
#pragma unroll
    for (int st = 1; st < 64; st <<= 1) v += __shfl_xor(v, st, 64);
    return v;
}

// ---------------------------------------------------------------------------
// K0: prep_planes — f32 -> fp16 h plane, pre-tiled + pre-swizzled.
// ---------------------------------------------------------------------------
__global__ __launch_bounds__(256) void prep_planes(const float* __restrict__ srcE,
                                                   const float* __restrict__ tgtE,
                                                   short* __restrict__ Ah,
                                                   short* __restrict__ Bh,
                                                   int* __restrict__ count) {
    int kt = blockIdx.x & 15, ng = blockIdx.x >> 4;
    int b = blockIdx.y, mat = blockIdx.z;
    int t = threadIdx.x;
    if (blockIdx.x == 0 && b == 0 && mat == 0 && t == 0) count[0] = 0;
    int nloc = t & 63, gg = t >> 6;
    int n = ng * 64 + nloc;
    int d0 = kt * 32 + gg * 8;
    const float* src = (mat ? tgtE : srcE) + (size_t)b * DD * NN;
    short* PH = mat ? Bh : Ah;

    float x[8];
#pragma unroll
    for (int j = 0; j < 8; j++) x[j] = src[(size_t)(d0 + j) * NN + n];
    unsigned h4[4];
#pragma unroll
    for (int p = 0; p < 4; p++) {
        _Float16 h0 = (_Float16)x[2 * p], h1 = (_Float16)x[2 * p + 1];  // RNE
        h4[p] = (unsigned)__builtin_bit_cast(unsigned short, h0) |
                ((unsigned)__builtin_bit_cast(unsigned short, h1) << 16);
    }
    size_t o = ((size_t)(b * 16 + kt) * NN + n) * 32 + ((gg ^ ((n >> 1) & 3)) << 3);
    *(uint4*)&PH[o] = (uint4){h4[0], h4[1], h4[2], h4[3]};
}

// ---------------------------------------------------------------------------
// K1: depth-2 pipelined MFMA GEMM (fp16 1-product): ring of 3 LDS buffers,
// counted vmcnt(4) + ONE raw s_barrier per iteration + top-2/argmax epilogue.
// Single-barrier proof: STAGE((kt+2)%3) overwrites buf[(kt-1)%3], whose
// readers finished before reaching this iteration's barrier; a fast wave
// blocks at the next barrier before it can stage over a buffer still in use.
// ---------------------------------------------------------------------------
__global__ __launch_bounds__(256) void gemm_fused(const short* __restrict__ Ah,
                                                  const short* __restrict__ Bh,
                                                  float* __restrict__ part) {
    int b = blockIdx.z;
    int id = blockIdx.y * 16 + blockIdx.x;
    int swz = (id & 7) * 32 + (id >> 3);  // XCD-bijective (256 % 8 == 0)
    int bx = swz & 15, by = swz >> 4;
    int n0 = by * 128, m0 = bx * 128;

    __shared__ short LDS[3][2][4096];  // ring of 3 x [plane: Ah Bh] = 48 KB

    int t = threadIdx.x, w = t >> 6, lane = t & 63;
    int wr = w >> 1, wc = w & 1;
    int fr = lane & 15, kq = lane >> 4;

    const short* gpl[2] = {Ah, Bh};

    f32x4 acc[4][4];
#pragma unroll
    for (int i = 0; i < 4; i++)
#pragma unroll
        for (int j = 0; j < 4; j++) acc[i][j] = (f32x4){0.f, 0.f, 0.f, 0.f};

    auto STAGE = [&](int buf, int kt) {
#pragma unroll
        for (int q = 0; q < 4; q++) {
            int p = q >> 1, h = q & 1;
            int rb = (p == 0) ? n0 : m0;
            const short* g = gpl[p] + ((size_t)(b * 16 + kt) * NN + rb) * 32 +
                             h * 2048 + w * 512 + lane * 8;
            __builtin_amdgcn_global_load_lds(
                (const __attribute__((address_space(1))) void*)g,
                (__attribute__((address_space(3))) void*)&LDS[buf][p][h * 2048 + w * 512],
                16, 0, 0);
        }
    };

    STAGE(0, 0);
    STAGE(1, 1);  // 8 loads in flight
    for (int kt = 0; kt < 16; kt++) {
        // wait for THIS tile's 4 loads only; next tile's 4 stay in flight
        if (kt < 15) {
            asm volatile("s_waitcnt vmcnt(4)" ::: "memory");
        } else {
            asm volatile("s_waitcnt vmcnt(0)" ::: "memory");
        }
        __builtin_amdgcn_s_barrier();      // all waves' loads for buf[kt%3] done
        __builtin_amdgcn_sched_barrier(0); // pin ds_reads after the waitcnt

        int cur = kt % 3;
        f16x8 ah[4], bh[4];
#pragma unroll
        for (int i = 0; i < 4; i++) {
            int rA = wr * 64 + i * 16 + fr;
            int offA = rA * 32 + ((kq ^ ((rA >> 1) & 3)) << 3);
            ah[i] = *(const f16x8*)&LDS[cur][0][offA];
            int rB = wc * 64 + i * 16 + fr;
            int offB = rB * 32 + ((kq ^ ((rB >> 1) & 3)) << 3);
            bh[i] = *(const f16x8*)&LDS[cur][1][offB];
        }
#pragma unroll
        for (int i = 0; i < 4; i++)
#pragma unroll
            for (int j = 0; j < 4; j++)
                acc[i][j] = __builtin_amdgcn_mfma_f32_16x16x32_f16(ah[i], bh[j],
                                                                   acc[i][j], 0, 0, 0);
        if (kt < 14) STAGE((kt + 2) % 3, kt + 2);
    }

    // ---- top-2/argmax epilogue ----
    int t32 = bx * 2 + wc;
#pragma unroll
    for (int i = 0; i < 4; i++) {
#pragma unroll
        for (int rg = 0; rg < 4; rg++) {
            int row = n0 + wr * 64 + i * 16 + kq * 4 + rg;
            float m1 = -3.4e38f, m2 = -3.4e38f;
            int i1 = 0x7fffffff;
#pragma unroll
            for (int j = 0; j < 4; j++) {
                float vv = __fmul_rn(10000.0f, __fdiv_rn(acc[i][j][rg], 22.627416997969522f));
                int col = m0 + wc * 64 + j * 16 + fr;
                if (vv > m1) { m2 = m1; m1 = vv; i1 = col; }
                else if (vv > m2) m2 = vv;
            }
#pragma unroll
            for (int st = 1; st < 16; st <<= 1) {
                float om1 = __shfl_xor(m1, st, 64);
                float om2 = __shfl_xor(m2, st, 64);
                int oi1 = __shfl_xor(i1, st, 64);
                if (om1 > m1 || (om1 == m1 && oi1 < i1)) {
                    m2 = fmaxf(m1, om2); m1 = om1; i1 = oi1;
                } else {
                    m2 = fmaxf(om1, m2);
                }
            }
            if (fr == 0) {
                size_t o = ((size_t)(b * NN + row) * 32 + t32) * 4;
                *(float4*)&part[o] = (float4){m1, m2, (float)i1, 0.f};
            }
        }
    }
}

// ---------------------------------------------------------------------------
// K2: merge partials -> corres0, flags; push PRUNED (row,tile) refine items;
// gather corrTgt = tgt[:, corres0]
// ---------------------------------------------------------------------------
__global__ __launch_bounds__(256) void combine_rows(const float* __restrict__ part,
                                                    const float* __restrict__ tgtP,
                                                    int* __restrict__ corres,
                                                    int* __restrict__ flags,
                                                    int* __restrict__ list,
                                                    int* __restrict__ count,
                                                    unsigned long long* __restrict__ keys,
                                                    float* __restrict__ corrTgt) {
    int b = blockIdx.y;
    int w = threadIdx.x >> 6, lane = threadIdx.x & 63;
    int n = blockIdx.x * 4 + w;
    int row = b * NN + n;
    float m1 = -3.4e38f, m2 = -3.4e38f;
    int i1 = 0x7fffffff;
    if (lane < 32) {
        float4 p1 = *(const float4*)&part[((size_t)row * 32 + lane) * 4];
        m1 = p1.x; m2 = p1.y; i1 = (int)p1.z;
    }
    float tm1 = m1;  // per-lane tile max, preserved through the reduction
#pragma unroll
    for (int st = 1; st < 64; st <<= 1) {
        float om1 = __shfl_xor(m1, st, 64);
        float om2 = __shfl_xor(m2, st, 64);
        int oi1 = __shfl_xor(i1, st, 64);
        if (om1 > m1 || (om1 == m1 && oi1 < i1)) {
            m2 = fmaxf(m1, om2); m1 = om1; i1 = oi1;
        } else {
            m2 = fmaxf(om1, m2);
        }
    }
    // fp16 1-product error sigma ~4.7 sv per score; flag if gap < 34 (~5 sigma)
    int fl = (__fsub_rn(m1, m2) < 34.0f) ? 1 : 0;
    // tile-prune: margin must cover |err(c1)|+|err(c*)| (sigma~6.6) -> 44
    bool pred = fl && (lane < 32) && (tm1 >= __fsub_rn(m1, 44.0f));
    unsigned long long mask = __ballot(pred);
    int base = 0;
    if (fl) {
        if (lane == 0) {
            flags[row] = 1;
            keys[row] = 0ull;  // refine runs later in stream order
            base = atomicAdd(count, __popcll(mask));
        }
        base = __shfl(base, 0, 64);
        if (pred) {
            int rank = __popcll(mask & ((1ull << lane) - 1ull));
            list[base + rank] = (row << 5) | lane;  // (row, tile)
        }
    } else if (lane == 0) {
        flags[row] = 0;
    }
    if (lane == 0) {
        corres[row] = i1;
        const float* tb = tgtP + (size_t)b * 3 * NN;
        corrTgt[(size_t)row * 3 + 0] = tb[i1];
        corrTgt[(size_t)row * 3 + 1] = tb[NN + i1];
        corrTgt[(size_t)row * 3 + 2] = tb[2 * NN + i1];
    }
}

// ---------------------------------------------------------------------------
// K2b: tile-pruned exact-f32 argmax refine. Item = (row, 64-col tile);
// 256 threads = 64 cols x 4-way K-split; A-col in LDS; atomicMax packed key.
// ---------------------------------------------------------------------------
__global__ __launch_bounds__(256) void refine_tiles(const float* __restrict__ A,
                                                    const float* __restrict__ Bm,
                                                    const int* __restrict__ list,
                                                    const int* __restrict__ count,
                                                    unsigned long long* __restrict__ keys) {
    int tid = threadIdx.x;
    int c = tid & 63, ks = tid >> 6;
    __shared__ float Acol[DD];
    __shared__ float partial[4][64];
    int nitems = count[0];
    for (int item = blockIdx.x; item < nitems; item += 2048) {
        int code = list[item];
        int row = code >> 5, tile = code & 31;
        int b = row / NN, n = row % NN;
        const float* Ab = A + (size_t)b * DD * NN;
        const float* Bb = Bm + (size_t)b * DD * NN;
        Acol[tid] = Ab[(size_t)tid * NN + n];
        Acol[tid + 256] = Ab[(size_t)(tid + 256) * NN + n];
        __syncthreads();
        int m = tile * 64 + c;
        float acc = 0.f;
        int dbase = ks * 128;
        for (int d = 0; d < 128; d++)
            acc = fmaf(Acol[dbase + d], Bb[(size_t)(dbase + d) * NN + m], acc);
        partial[ks][c] = acc;
        __syncthreads();
        if (tid < 64) {  // one wave finishes: sum K-splits, pack key, reduce
            float tot = __fadd_rn(__fadd_rn(partial[0][c], partial[1][c]),
                                  __fadd_rn(partial[2][c], partial[3][c]));
            float sc = __fmul_rn(10000.0f, __fdiv_rn(tot, 22.627416997969522f));
            unsigned u = __float_as_uint(sc);
            u = (u & 0x80000000u) ? ~u : (u | 0x80000000u);  // order-preserving
            unsigned long long key =
                ((unsigned long long)u << 32) | (unsigned)(~(unsigned)m);
#pragma unroll
            for (int st = 1; st < 64; st <<= 1) {
                unsigned long long ok = __shfl_xor((long long)key, st, 64);
                if (ok > key) key = ok;
            }
            if (c == 0) atomicMax(&keys[row], key);
        }
        __syncthreads();
    }
}

// ---------------------------------------------------------------------------
// K3: GFM — 512 threads, 8 points/block (1 per wave).  AoS float4 cloud in
// LDS + packed u32 keys; extraction via subtract-domain scan (keys unique &
// extracted in increasing order: rel = key-(prev+1) wraps removed keys huge).
// Bit-identical selection to the masked-scan version.
// ---------------------------------------------------------------------------
__global__ __launch_bounds__(512) void gfm_kernel(const float* __restrict__ srcP,
                                                  const float* __restrict__ corrTgt,
                                                  float* __restrict__ pointLoss) {
    int b = blockIdx.y, tid = threadIdx.x;
    int w = tid >> 6, lane = tid & 63;
    int n = blockIdx.x * 8 + w;
    __shared__ float4 XP[NN];  // {x, y, z, sq} = 32 KB
    __shared__ int nbl[8][KNB];
    __shared__ float ptb[8][KNB][3];
    __shared__ float la[8][NPAIR], rg[8][NPAIR], srt[8][NPAIR];
    const float* xs = srcP + (size_t)b * 3 * NN;

    for (int i = tid; i < NN / 4; i += 512) {
        float4 u0 = ((const float4*)xs)[i];
        float4 u1 = ((const float4*)(xs + NN))[i];
        float4 u2 = ((const float4*)(xs + 2 * NN))[i];
        float4 q;
        q.x = __fadd_rn(__fadd_rn(__fmul_rn(u0.x, u0.x), __fmul_rn(u1.x, u1.x)), __fmul_rn(u2.x, u2.x));
        q.y = __fadd_rn(__fadd_rn(__fmul_rn(u0.y, u0.y), __fmul_rn(u1.y, u1.y)), __fmul_rn(u2.y, u2.y));
        q.z = __fadd_rn(__fadd_rn(__fmul_rn(u0.z, u0.z), __fmul_rn(u1.z, u1.z)), __fmul_rn(u2.z, u2.z));
        q.w = __fadd_rn(__fadd_rn(__fmul_rn(u0.w, u0.w), __fmul_rn(u1.w, u1.w)), __fmul_rn(u2.w, u2.w));
        XP[4 * i + 0] = (float4){u0.x, u1.x, u2.x, q.x};
        XP[4 * i + 1] = (float4){u0.y, u1.y, u2.y, q.y};
        XP[4 * i + 2] = (float4){u0.z, u1.z, u2.z, q.z};
        XP[4 * i + 3] = (float4){u0.w, u1.w, u2.w, q.w};
    }
    __syncthreads();

    float4 av = XP[n];
    float a0 = av.x, a1 = av.y, a2 = av.z, sqa = av.w;
    unsigned key[32];
#pragma unroll
    for (int r = 0; r < 32; r++) {
        int m = lane + 64 * r;
        float4 p = XP[m];
        float dot = __fadd_rn(__fadd_rn(__fmul_rn(a0, p.x), __fmul_rn(a1, p.y)),
                              __fmul_rn(a2, p.z));
        float d2 = __fsub_rn(__fadd_rn(sqa, p.w), __fmul_rn(2.0f, dot));
        d2 = fmaxf(d2, 0.0f);
        key[r] = (__float_as_uint(d2) & 0xFFFFF800u) | (unsigned)m;  // < 2^31
    }
    unsigned prev1 = 0;  // prev extracted key + 1 (0 on first iteration)
#pragma unroll
    for (int it = 0; it < KNB; it++) {
        unsigned best = 0xFFFFFFFFu;
#pragma unroll
        for (int r = 0; r < 32; r++)
            best = min(best, key[r] - prev1);  // removed/smaller keys wrap huge
#pragma unroll
        for (int st = 1; st < 64; st <<= 1) {
            unsigned ob = __shfl_xor((int)best, st, 64);
            best = min(best, ob);
        }
        unsigned abskey = best + prev1;
        int m = (int)(abskey & 2047u);
        if (lane == 0) nbl[w][it] = m;
        prev1 = abskey + 1u;
    }
    __builtin_amdgcn_wave_barrier();
    if (lane < KNB) {
        int ia = nbl[w][lane];
        const float* ct = corrTgt + ((size_t)b * NN + ia) * 3;
        ptb[w][lane][0] = ct[0];
        ptb[w][lane][1] = ct[1];
        ptb[w][lane][2] = ct[2];
    }
    __builtin_amdgcn_wave_barrier();
    const float* ctn = corrTgt + ((size_t)b * NN + n) * 3;
    float t0 = ctn[0], t1 = ctn[1], t2 = ctn[2];
    if (lane < NPAIR) {
        int k = lane, ja = 0, cnt = 9;
        while (k >= cnt) { k -= cnt; ja++; cnt--; }
        int jb = ja + 1 + k;
        int ia = nbl[w][ja], ib = nbl[w][jb];
        float4 pa = XP[ia], pb = XP[ib];
        float area_s = tri_area(a0, a1, a2, pa.x, pa.y, pa.z, pb.x, pb.y, pb.z);
        float area_t = tri_area(t0, t1, t2, ptb[w][ja][0], ptb[w][ja][1], ptb[w][ja][2],
                                ptb[w][jb][0], ptb[w][jb][1], ptb[w][jb][2]);
        const float EPSF = 1e-6f;
        float ee = __fmul_rn(EPSF, EPSF);
        float lt2 = __fadd_rn(area_t, EPSF);
        float da = __fsub_rn(area_s, lt2);
        float sa = __fadd_rn(area_s, lt2);
        float num = __fadd_rn(__fadd_rn(ee, ee), __fmul_rn(da, da));
        float den = __fadd_rn(__fadd_rn(ee, ee), __fmul_rn(sa, sa));
        la[w][lane] = __fdiv_rn(num, den);
        rg[w][lane] = sqrtf(num);
    }
    __builtin_amdgcn_wave_barrier();
    if (lane < NPAIR) {
        float x = la[w][lane];
        int rk = 0;
        for (int j = 0; j < NPAIR; j++) {
            float y = la[w][j];
            rk += (y < x || (y == x && j < lane)) ? 1 : 0;
        }
        srt[w][rk] = x;
    }
    __builtin_amdgcn_wave_barrier();
    float l2v = 0.f;
    if (lane < NPAIR) l2v = __fadd_rn(srt[w][lane], __fmul_rn(0.1f, rg[w][lane]));
    __builtin_amdgcn_wave_barrier();
    if (lane < NPAIR) la[w][lane] = l2v;
    __builtin_amdgcn_wave_barrier();
    if (lane < NPAIR) {
        float x = la[w][lane];
        int rk = 0;
        for (int j = 0; j < NPAIR; j++) {
            float y = la[w][j];
            rk += (y < x || (y == x && j < lane)) ? 1 : 0;
        }
        srt[w][rk] = x;
    }
    __builtin_amdgcn_wave_barrier();
    float med = srt[w][22];
    float thr = __fmul_rn(3.0f, med);
    float term = 0.f;
    if (lane < KNB) {
        float vv = la[w][lane];
        if (vv > thr) vv = 0.f;
        term = sqrtf(__fadd_rn(vv, 1e-6f));
    }
#pragma unroll
    for (int st = 1; st < 64; st <<= 1) term += __shfl_xor(term, st, 64);
    if (lane == 0) pointLoss[b * NN + n] = __fdiv_rn(term, 10.0f);
}

// ---------------------------------------------------------------------------
// K4: fused finish — 1024 threads/batch: refined corres, min, weight,
// Procrustes reductions, 3x3 Jacobi SVD
// ---------------------------------------------------------------------------
__device__ double det3(const double M[3][3]) {
    return M[0][0] * (M[1][1] * M[2][2] - M[1][2] * M[2][1]) -
           M[0][1] * (M[1][0] * M[2][2] - M[1][2] * M[2][0]) +
           M[0][2] * (M[1][0] * M[2][1] - M[1][1] * M[2][0]);
}

__global__ __launch_bounds__(1024) void fused_finish(const float* __restrict__ pointLoss,
                                                     const int* __restrict__ flags,
                                                     const unsigned long long* __restrict__ keys,
                                                     const int* __restrict__ corresIn,
                                                     const float* __restrict__ srcP,
                                                     const float* __restrict__ tgtP,
                                                     float* __restrict__ outR,
                                                     float* __restrict__ outT,
                                                     float* __restrict__ outC,
                                                     float* __restrict__ outW) {
    int b = blockIdx.x, tid = threadIdx.x;
    int w = tid >> 6, lane = tid & 63;
    __shared__ int csh[NN];
    __shared__ float wsh[NN];
    __shared__ float fred[1024];
    __shared__ double sd[16][9];
    __shared__ double sxySh[9];

    // phase 1: final corres (apply refined keys) + min(pointLoss)
    float mn = 3.4e38f;
    for (int n = tid; n < NN; n += 1024) {
        int row = b * NN + n;
        int ci = corresIn[row];
        if (flags[row]) ci = (int)(~(unsigned)(keys[row] & 0xFFFFFFFFull));
        csh[n] = ci;
        outC[row] = (float)ci;
        mn = fminf(mn, pointLoss[row]);
    }
    fred[tid] = mn;
    __syncthreads();
    for (int st = 512; st > 0; st >>= 1) {
        if (tid < st) fred[tid] = fminf(fred[tid], fred[tid + st]);
        __syncthreads();
    }
    float minL = fred[0];
    __syncthreads();

    // phase 2: weight
    for (int n = tid; n < NN; n += 1024) {
        int row = b * NN + n;
        float l = __fsub_rn(pointLoss[row], minL);
        float z = __fmul_rn(-20.0f, l);
        float ez = expf(z);
        float sg = __fdiv_rn(ez, __fadd_rn(1.0f, ez));
        float wf = (__fmul_rn(2.0f, sg) > 0.5f) ? 1.0f : 0.0f;
        wsh[n] = wf;
        outW[row] = wf;
    }
    __syncthreads();

    // phase 3: Procrustes reductions (double, 16 waves)
    const float* xs = srcP + (size_t)b * 3 * NN;
    const float* ts = tgtP + (size_t)b * 3 * NN;
    double acc7[7] = {0, 0, 0, 0, 0, 0, 0};
    for (int n = tid; n < NN; n += 1024) {
        if (wsh[n] != 0.0f) {
            acc7[0] += 1.0;
            acc7[1] += (double)xs[n];
            acc7[2] += (double)xs[NN + n];
            acc7[3] += (double)xs[2 * NN + n];
            int m = csh[n];
            acc7[4] += (double)ts[m];
            acc7[5] += (double)ts[NN + m];
            acc7[6] += (double)ts[2 * NN + m];
        }
    }
#pragma unroll
    for (int q = 0; q < 7; q++) {
        double r = wave_red_sum_d(acc7[q]);
        if (lane == 0) sd[w][q] = r;
    }
    __syncthreads();
    double tot7[7];
#pragma unroll
    for (int q = 0; q < 7; q++) {
        double s2 = 0;
#pragma unroll
        for (int w2 = 0; w2 < 16; w2++) s2 += sd[w2][q];
        tot7[q] = s2;
    }
    __syncthreads();

    double W1e = tot7[0] + 1e-7;
    double mux0 = tot7[1] / W1e, mux1 = tot7[2] / W1e, mux2 = tot7[3] / W1e;
    double muy0 = tot7[4] / W1e, muy1 = tot7[5] / W1e, muy2 = tot7[6] / W1e;

    double s[9] = {0, 0, 0, 0, 0, 0, 0, 0, 0};
    for (int n = tid; n < NN; n += 1024) {
        if (wsh[n] != 0.0f) {
            double dx0 = (double)xs[n] - mux0;
            double dx1 = (double)xs[NN + n] - mux1;
            double dx2 = (double)xs[2 * NN + n] - mux2;
            int m = csh[n];
            double dy0 = (double)ts[m] - muy0;
            double dy1 = (double)ts[NN + m] - muy1;
            double dy2 = (double)ts[2 * NN + m] - muy2;
            s[0] += dy0 * dx0; s[1] += dy0 * dx1; s[2] += dy0 * dx2;
            s[3] += dy1 * dx0; s[4] += dy1 * dx1; s[5] += dy1 * dx2;
            s[6] += dy2 * dx0; s[7] += dy2 * dx1; s[8] += dy2 * dx2;
        }
    }
#pragma unroll
    for (int q = 0; q < 9; q++) {
        double r = wave_red_sum_d(s[q]);
        if (lane == 0) sd[w][q] = r;
    }
    __syncthreads();
    if (tid < 9) {
        double s2 = 0;
#pragma unroll
        for (int w2 = 0; w2 < 16; w2++) s2 += sd[w2][tid];
        sxySh[tid] = s2 / W1e;
    }
    __syncthreads();

    // phase 4: one thread does the 3x3 Jacobi SVD -> R, T
    if (tid == 0) {
        double Bm2[3][3], V[3][3];
        for (int r = 0; r < 3; r++)
            for (int c2 = 0; c2 < 3; c2++) {
                Bm2[r][c2] = sxySh[r * 3 + c2];
                V[r][c2] = (r == c2) ? 1.0 : 0.0;
            }
        double nrm2 = 0;
        for (int r = 0; r < 3; r++)
            for (int c2 = 0; c2 < 3; c2++) nrm2 += Bm2[r][c2] * Bm2[r][c2];

        for (int sweep = 0; sweep < 60; sweep++) {
            double off = 0;
            for (int p = 0; p < 2; p++) {
                for (int q = p + 1; q < 3; q++) {
                    double al = 0, be = 0, ga = 0;
                    for (int i = 0; i < 3; i++) {
                        al += Bm2[i][p] * Bm2[i][p];
                        be += Bm2[i][q] * Bm2[i][q];
                        ga += Bm2[i][p] * Bm2[i][q];
                    }
                    off += ga * ga;
                    if (fabs(ga) > 1e-300) {
                        double ze = (be - al) / (2.0 * ga);
                        double tt = copysign(1.0, ze) / (fabs(ze) + sqrt(1.0 + ze * ze));
                        double c = 1.0 / sqrt(1.0 + tt * tt), sn = c * tt;
                        for (int i = 0; i < 3; i++) {
                            double bp = Bm2[i][p], bq = Bm2[i][q];
                            Bm2[i][p] = c * bp - sn * bq;
                            Bm2[i][q] = sn * bp + c * bq;
                            double vp = V[i][p], vq = V[i][q];
                            V[i][p] = c * vp - sn * vq;
                            V[i][q] = sn * vp + c * vq;
                        }
                    }
                }
            }
            if (off <= 1e-30 * nrm2 * nrm2) break;
        }
        double sig[3];
        for (int j = 0; j < 3; j++) {
            double ss = 0;
            for (int i = 0; i < 3; i++) ss += Bm2[i][j] * Bm2[i][j];
            sig[j] = sqrt(ss);
        }
        for (int a = 0; a < 2; a++)
            for (int j = 0; j < 2 - a; j++)
                if (sig[j] < sig[j + 1]) {
                    double t2 = sig[j]; sig[j] = sig[j + 1]; sig[j + 1] = t2;
                    for (int i = 0; i < 3; i++) {
                        double tb = Bm2[i][j]; Bm2[i][j] = Bm2[i][j + 1]; Bm2[i][j + 1] = tb;
                        double tv = V[i][j]; V[i][j] = V[i][j + 1]; V[i][j + 1] = tv;
                    }
                }
        double U[3][3];
        for (int j = 0; j < 3; j++) {
            double inv = (sig[j] > 1e-150) ? 1.0 / sig[j] : 0.0;
            for (int i = 0; i < 3; i++) U[i][j] = Bm2[i][j] * inv;
        }
        if (sig[2] <= 1e-10 * (sig[0] + 1e-300)) {
            double u0 = U[1][0] * U[2][1] - U[2][0] * U[1][1];
            double u1 = U[2][0] * U[0][1] - U[0][0] * U[2][1];
            double u2 = U[0][0] * U[1][1] - U[1][0] * U[0][1];
            double nr = sqrt(u0 * u0 + u1 * u1 + u2 * u2);
            if (nr > 1e-150) { U[0][2] = u0 / nr; U[1][2] = u1 / nr; U[2][2] = u2 / nr; }
        }
        double dU = det3(U), dV = det3(V);
        double s3 = (dU * dV >= 0.0) ? 1.0 : -1.0;
        double R[3][3];
        for (int i = 0; i < 3; i++)
            for (int j = 0; j < 3; j++)
                R[i][j] = U[i][0] * V[j][0] + U[i][1] * V[j][1] + s3 * U[i][2] * V[j][2];
        double mux[3] = {mux0, mux1, mux2};
        double muy[3] = {muy0, muy1, muy2};
        for (int i = 0; i < 3; i++) {
            for (int j = 0; j < 3; j++) outR[b * 9 + i * 3 + j] = (float)R[i][j];
            double t2 = muy[i] - (R[i][0] * mux[0] + R[i][1] * mux[1] + R[i][2] * mux[2]);
            outT[b * 3 + i] = (float)t2;
        }
    }
}

// ---------------------------------------------------------------------------
// host launcher
// ---------------------------------------------------------------------------
extern "C" void kernel_launch(void* const* d_in, const int* in_sizes, int n_in,
                              void* d_out, int out_size, void* d_ws, size_t ws_size,
                              hipStream_t stream) {
    const float* srcE = (const float*)d_in[0];
    const float* tgtE = (const float*)d_in[1];
    const float* srcP = (const float*)d_in[2];
    const float* tgtP = (const float*)d_in[3];
    float* out = (float*)d_out;  // R[36] T[12] corres[8192] weight[8192]

    char* w = (char*)d_ws;
    size_t off = 0;
    auto alloc = [&](size_t bytes) -> void* {
        void* p = w + off;
        off = (off + bytes + 255) & ~(size_t)255;
        return p;
    };
    float* corrTgt = (float*)alloc((size_t)NBATCH * NN * 3 * 4);
    int* corres = (int*)alloc((size_t)NBATCH * NN * 4);
    int* flags = (int*)alloc((size_t)NBATCH * NN * 4);
    unsigned long long* keys = (unsigned long long*)alloc((size_t)NBATCH * NN * 8);
    int* list = (int*)alloc((size_t)NBATCH * NN * 32 * 4);  // worst-case all tiles
    int* count = (int*)alloc(256);
    float* pointLoss = (float*)alloc((size_t)NBATCH * NN * 4);
    size_t planeShorts = (size_t)NBATCH * 16 * NN * 32;  // 8.4 MB per plane
    short* Ah = (short*)alloc(planeShorts * 2);
    short* Bh = (short*)alloc(planeShorts * 2);
    float* part = (float*)alloc((size_t)NBATCH * NN * 32 * 4 * 4);  // 4.2 MB

    prep_planes<<<dim3(512, NBATCH, 2), 256, 0, stream>>>(srcE, tgtE, Ah, Bh, count);
    gemm_fused<<<dim3(NN / 128, NN / 128, NBATCH), 256, 0, stream>>>(Ah, Bh, part);
    combine_rows<<<dim3(NN / 4, NBATCH), 256, 0, stream>>>(part, tgtP, corres, flags, list,
                                                           count, keys, corrTgt);
    gfm_kernel<<<dim3(NN / 8, NBATCH), 512, 0, stream>>>(srcP, corrTgt, pointLoss);
    refine_tiles<<<dim3(2048), 256, 0, stream>>>(srcE, tgtE, list, count, keys);
    fused_finish<<<NBATCH, 1024, 0, stream>>>(pointLoss, flags, keys, corres, srcP, tgtP,
                                              out, out + 36, out + 48, out + 48 + NBATCH * NN);
}

// Round 19
// 118.276 us; speedup vs baseline: 1.2232x; 1.0106x over previous
//
#include <hip/hip_runtime.h>
#include <hip/hip_bf16.h>

#define NN 2048
#define DD 512
#define NBATCH 4
#define KNB 10
#define NPAIR 45

typedef __attribute__((ext_vector_type(8))) _Float16 f16x8;
typedef __attribute__((ext_vector_type(4))) float f32x4;

// ---------------------------------------------------------------------------
// helpers
// ---------------------------------------------------------------------------
__device__ __forceinline__ float tri_area(float p0x, float p0y, float p0z,
                                          float p1x, float p1y, float p1z,
                                          float p2x, float p2y, float p2z) {
    float e1x = __fsub_rn(p1x, p0x), e1y = __fsub_rn(p1y, p0y), e1z = __fsub_rn(p1z, p0z);
    float e2x = __fsub_rn(p2x, p0x), e2y = __fsub_rn(p2y, p0y), e2z = __fsub_rn(p2z, p0z);
    float c0 = __fsub_rn(__fmul_rn(e1y, e2z), __fmul_rn(e1z, e2y));
    float c1 = __fsub_rn(__fmul_rn(e1z, e2x), __fmul_rn(e1x, e2z));
    float c2 = __fsub_rn(__fmul_rn(e1x, e2y), __fmul_rn(e1y, e2x));
    float ss = __fadd_rn(__fadd_rn(__fmul_rn(c0, c0), __fmul_rn(c1, c1)), __fmul_rn(c2, c2));
    return __fmul_rn(0.5f, sqrtf(ss));
}

__device__ __forceinline__ double wave_red_sum_d(double v) {
#pragma unroll
    for (int st = 1; st < 64; st <<= 1) v += __shfl_xor(v, st, 64);
    return v;
}

// ---------------------------------------------------------------------------
// K0: prep_planes — f32 -> fp16 h plane, pre-tiled + pre-swizzled.
// ---------------------------------------------------------------------------
__global__ __launch_bounds__(256) void prep_planes(const float* __restrict__ srcE,
                                                   const float* __restrict__ tgtE,
                                                   short* __restrict__ Ah,
                                                   short* __restrict__ Bh,
                                                   int* __restrict__ count) {
    int kt = blockIdx.x & 15, ng = blockIdx.x >> 4;
    int b = blockIdx.y, mat = blockIdx.z;
    int t = threadIdx.x;
    if (blockIdx.x == 0 && b == 0 && mat == 0 && t == 0) count[0] = 0;
    int nloc = t & 63, gg = t >> 6;
    int n = ng * 64 + nloc;
    int d0 = kt * 32 + gg * 8;
    const float* src = (mat ? tgtE : srcE) + (size_t)b * DD * NN;
    short* PH = mat ? Bh : Ah;

    float x[8];
#pragma unroll
    for (int j = 0; j < 8; j++) x[j] = src[(size_t)(d0 + j) * NN + n];
    unsigned h4[4];
#pragma unroll
    for (int p = 0; p < 4; p++) {
        _Float16 h0 = (_Float16)x[2 * p], h1 = (_Float16)x[2 * p + 1];  // RNE
        h4[p] = (unsigned)__builtin_bit_cast(unsigned short, h0) |
                ((unsigned)__builtin_bit_cast(unsigned short, h1) << 16);
    }
    size_t o = ((size_t)(b * 16 + kt) * NN + n) * 32 + ((gg ^ ((n >> 1) & 3)) << 3);
    *(uint4*)&PH[o] = (uint4){h4[0], h4[1], h4[2], h4[3]};
}

// ---------------------------------------------------------------------------
// K1: depth-2 pipelined MFMA GEMM (fp16 1-product): ring of 3 LDS buffers,
// counted vmcnt(4) + ONE raw s_barrier per iteration + top-2/argmax epilogue.
// Full-grid XCD swizzle (includes batch): each XCD owns one batch's 8x16
// panel stripe -> 3 MB working set < 4 MB L2 (was 9 MB with per-slice swz).
// ---------------------------------------------------------------------------
__global__ __launch_bounds__(256) void gemm_fused(const short* __restrict__ Ah,
                                                  const short* __restrict__ Bh,
                                                  float* __restrict__ part) {
    // linear id over all 1024 blocks (x + 16y + 256z); dispatch round-robins
    // XCDs by this id, so chunk by (gid & 7)
    int gid = blockIdx.x + (blockIdx.y << 4) + (blockIdx.z << 8);
    int nid = (gid & 7) * 128 + (gid >> 3);  // bijective: 1024 = 8 * 128
    int b = nid >> 8;
    int rem = nid & 255;
    int bx = rem & 15, by = rem >> 4;
    int n0 = by * 128, m0 = bx * 128;

    __shared__ short LDS[3][2][4096];  // ring of 3 x [plane: Ah Bh] = 48 KB

    int t = threadIdx.x, w = t >> 6, lane = t & 63;
    int wr = w >> 1, wc = w & 1;
    int fr = lane & 15, kq = lane >> 4;

    const short* gpl[2] = {Ah, Bh};

    f32x4 acc[4][4];
#pragma unroll
    for (int i = 0; i < 4; i++)
#pragma unroll
        for (int j = 0; j < 4; j++) acc[i][j] = (f32x4){0.f, 0.f, 0.f, 0.f};

    auto STAGE = [&](int buf, int kt) {
#pragma unroll
        for (int q = 0; q < 4; q++) {
            int p = q >> 1, h = q & 1;
            int rb = (p == 0) ? n0 : m0;
            const short* g = gpl[p] + ((size_t)(b * 16 + kt) * NN + rb) * 32 +
                             h * 2048 + w * 512 + lane * 8;
            __builtin_amdgcn_global_load_lds(
                (const __attribute__((address_space(1))) void*)g,
                (__attribute__((address_space(3))) void*)&LDS[buf][p][h * 2048 + w * 512],
                16, 0, 0);
        }
    };

    STAGE(0, 0);
    STAGE(1, 1);  // 8 loads in flight
    for (int kt = 0; kt < 16; kt++) {
        // wait for THIS tile's 4 loads only; next tile's 4 stay in flight
        if (kt < 15) {
            asm volatile("s_waitcnt vmcnt(4)" ::: "memory");
        } else {
            asm volatile("s_waitcnt vmcnt(0)" ::: "memory");
        }
        __builtin_amdgcn_s_barrier();      // all waves' loads for buf[kt%3] done
        __builtin_amdgcn_sched_barrier(0); // pin ds_reads after the waitcnt

        int cur = kt % 3;
        f16x8 ah[4], bh[4];
#pragma unroll
        for (int i = 0; i < 4; i++) {
            int rA = wr * 64 + i * 16 + fr;
            int offA = rA * 32 + ((kq ^ ((rA >> 1) & 3)) << 3);
            ah[i] = *(const f16x8*)&LDS[cur][0][offA];
            int rB = wc * 64 + i * 16 + fr;
            int offB = rB * 32 + ((kq ^ ((rB >> 1) & 3)) << 3);
            bh[i] = *(const f16x8*)&LDS[cur][1][offB];
        }
#pragma unroll
        for (int i = 0; i < 4; i++)
#pragma unroll
            for (int j = 0; j < 4; j++)
                acc[i][j] = __builtin_amdgcn_mfma_f32_16x16x32_f16(ah[i], bh[j],
                                                                   acc[i][j], 0, 0, 0);
        if (kt < 14) STAGE((kt + 2) % 3, kt + 2);
    }

    // ---- top-2/argmax epilogue ----
    int t32 = bx * 2 + wc;
#pragma unroll
    for (int i = 0; i < 4; i++) {
#pragma unroll
        for (int rg = 0; rg < 4; rg++) {
            int row = n0 + wr * 64 + i * 16 + kq * 4 + rg;
            float m1 = -3.4e38f, m2 = -3.4e38f;
            int i1 = 0x7fffffff;
#pragma unroll
            for (int j = 0; j < 4; j++) {
                float vv = __fmul_rn(10000.0f, __fdiv_rn(acc[i][j][rg], 22.627416997969522f));
                int col = m0 + wc * 64 + j * 16 + fr;
                if (vv > m1) { m2 = m1; m1 = vv; i1 = col; }
                else if (vv > m2) m2 = vv;
            }
#pragma unroll
            for (int st = 1; st < 16; st <<= 1) {
                float om1 = __shfl_xor(m1, st, 64);
                float om2 = __shfl_xor(m2, st, 64);
                int oi1 = __shfl_xor(i1, st, 64);
                if (om1 > m1 || (om1 == m1 && oi1 < i1)) {
                    m2 = fmaxf(m1, om2); m1 = om1; i1 = oi1;
                } else {
                    m2 = fmaxf(om1, m2);
                }
            }
            if (fr == 0) {
                size_t o = ((size_t)(b * NN + row) * 32 + t32) * 4;
                *(float4*)&part[o] = (float4){m1, m2, (float)i1, 0.f};
            }
        }
    }
}

// ---------------------------------------------------------------------------
// K2: merge partials -> corres0, flags; push PRUNED (row,tile) refine items;
// gather corrTgt = tgt[:, corres0]
// ---------------------------------------------------------------------------
__global__ __launch_bounds__(256) void combine_rows(const float* __restrict__ part,
                                                    const float* __restrict__ tgtP,
                                                    int* __restrict__ corres,
                                                    int* __restrict__ flags,
                                                    int* __restrict__ list,
                                                    int* __restrict__ count,
                                                    unsigned long long* __restrict__ keys,
                                                    float* __restrict__ corrTgt) {
    int b = blockIdx.y;
    int w = threadIdx.x >> 6, lane = threadIdx.x & 63;
    int n = blockIdx.x * 4 + w;
    int row = b * NN + n;
    float m1 = -3.4e38f, m2 = -3.4e38f;
    int i1 = 0x7fffffff;
    if (lane < 32) {
        float4 p1 = *(const float4*)&part[((size_t)row * 32 + lane) * 4];
        m1 = p1.x; m2 = p1.y; i1 = (int)p1.z;
    }
    float tm1 = m1;  // per-lane tile max, preserved through the reduction
#pragma unroll
    for (int st = 1; st < 64; st <<= 1) {
        float om1 = __shfl_xor(m1, st, 64);
        float om2 = __shfl_xor(m2, st, 64);
        int oi1 = __shfl_xor(i1, st, 64);
        if (om1 > m1 || (om1 == m1 && oi1 < i1)) {
            m2 = fmaxf(m1, om2); m1 = om1; i1 = oi1;
        } else {
            m2 = fmaxf(om1, m2);
        }
    }
    // fp16 1-product error sigma ~4.7 sv per score; flag if gap < 34 (~5 sigma)
    int fl = (__fsub_rn(m1, m2) < 34.0f) ? 1 : 0;
    // tile-prune: margin must cover |err(c1)|+|err(c*)| (sigma~6.6) -> 44
    bool pred = fl && (lane < 32) && (tm1 >= __fsub_rn(m1, 44.0f));
    unsigned long long mask = __ballot(pred);
    int base = 0;
    if (fl) {
        if (lane == 0) {
            flags[row] = 1;
            keys[row] = 0ull;  // refine runs later in stream order
            base = atomicAdd(count, __popcll(mask));
        }
        base = __shfl(base, 0, 64);
        if (pred) {
            int rank = __popcll(mask & ((1ull << lane) - 1ull));
            list[base + rank] = (row << 5) | lane;  // (row, tile)
        }
    } else if (lane == 0) {
        flags[row] = 0;
    }
    if (lane == 0) {
        corres[row] = i1;
        const float* tb = tgtP + (size_t)b * 3 * NN;
        corrTgt[(size_t)row * 3 + 0] = tb[i1];
        corrTgt[(size_t)row * 3 + 1] = tb[NN + i1];
        corrTgt[(size_t)row * 3 + 2] = tb[2 * NN + i1];
    }
}

// ---------------------------------------------------------------------------
// K2b: tile-pruned exact-f32 argmax refine. Item = (row, 64-col tile);
// 256 threads = 64 cols x 4-way K-split; A-col in LDS; atomicMax packed key.
// ---------------------------------------------------------------------------
__global__ __launch_bounds__(256) void refine_tiles(const float* __restrict__ A,
                                                    const float* __restrict__ Bm,
                                                    const int* __restrict__ list,
                                                    const int* __restrict__ count,
                                                    unsigned long long* __restrict__ keys) {
    int tid = threadIdx.x;
    int c = tid & 63, ks = tid >> 6;
    __shared__ float Acol[DD];
    __shared__ float partial[4][64];
    int nitems = count[0];
    for (int item = blockIdx.x; item < nitems; item += 2048) {
        int code = list[item];
        int row = code >> 5, tile = code & 31;
        int b = row / NN, n = row % NN;
        const float* Ab = A + (size_t)b * DD * NN;
        const float* Bb = Bm + (size_t)b * DD * NN;
        Acol[tid] = Ab[(size_t)tid * NN + n];
        Acol[tid + 256] = Ab[(size_t)(tid + 256) * NN + n];
        __syncthreads();
        int m = tile * 64 + c;
        float acc = 0.f;
        int dbase = ks * 128;
        for (int d = 0; d < 128; d++)
            acc = fmaf(Acol[dbase + d], Bb[(size_t)(dbase + d) * NN + m], acc);
        partial[ks][c] = acc;
        __syncthreads();
        if (tid < 64) {  // one wave finishes: sum K-splits, pack key, reduce
            float tot = __fadd_rn(__fadd_rn(partial[0][c], partial[1][c]),
                                  __fadd_rn(partial[2][c], partial[3][c]));
            float sc = __fmul_rn(10000.0f, __fdiv_rn(tot, 22.627416997969522f));
            unsigned u = __float_as_uint(sc);
            u = (u & 0x80000000u) ? ~u : (u | 0x80000000u);  // order-preserving
            unsigned long long key =
                ((unsigned long long)u << 32) | (unsigned)(~(unsigned)m);
#pragma unroll
            for (int st = 1; st < 64; st <<= 1) {
                unsigned long long ok = __shfl_xor((long long)key, st, 64);
                if (ok > key) key = ok;
            }
            if (c == 0) atomicMax(&keys[row], key);
        }
        __syncthreads();
    }
}

// ---------------------------------------------------------------------------
// K3: GFM — 512 threads, 8 points/block (1 per wave).  AoS float4 cloud in
// LDS + packed u32 keys; extraction via subtract-domain scan.
// ---------------------------------------------------------------------------
__global__ __launch_bounds__(512) void gfm_kernel(const float* __restrict__ srcP,
                                                  const float* __restrict__ corrTgt,
                                                  float* __restrict__ pointLoss) {
    int b = blockIdx.y, tid = threadIdx.x;
    int w = tid >> 6, lane = tid & 63;
    int n = blockIdx.x * 8 + w;
    __shared__ float4 XP[NN];  // {x, y, z, sq} = 32 KB
    __shared__ int nbl[8][KNB];
    __shared__ float ptb[8][KNB][3];
    __shared__ float la[8][NPAIR], rg[8][NPAIR], srt[8][NPAIR];
    const float* xs = srcP + (size_t)b * 3 * NN;

    for (int i = tid; i < NN / 4; i += 512) {
        float4 u0 = ((const float4*)xs)[i];
        float4 u1 = ((const float4*)(xs + NN))[i];
        float4 u2 = ((const float4*)(xs + 2 * NN))[i];
        float4 q;
        q.x = __fadd_rn(__fadd_rn(__fmul_rn(u0.x, u0.x), __fmul_rn(u1.x, u1.x)), __fmul_rn(u2.x, u2.x));
        q.y = __fadd_rn(__fadd_rn(__fmul_rn(u0.y, u0.y), __fmul_rn(u1.y, u1.y)), __fmul_rn(u2.y, u2.y));
        q.z = __fadd_rn(__fadd_rn(__fmul_rn(u0.z, u0.z), __fmul_rn(u1.z, u1.z)), __fmul_rn(u2.z, u2.z));
        q.w = __fadd_rn(__fadd_rn(__fmul_rn(u0.w, u0.w), __fmul_rn(u1.w, u1.w)), __fmul_rn(u2.w, u2.w));
        XP[4 * i + 0] = (float4){u0.x, u1.x, u2.x, q.x};
        XP[4 * i + 1] = (float4){u0.y, u1.y, u2.y, q.y};
        XP[4 * i + 2] = (float4){u0.z, u1.z, u2.z, q.z};
        XP[4 * i + 3] = (float4){u0.w, u1.w, u2.w, q.w};
    }
    __syncthreads();

    float4 av = XP[n];
    float a0 = av.x, a1 = av.y, a2 = av.z, sqa = av.w;
    unsigned key[32];
#pragma unroll
    for (int r = 0; r < 32; r++) {
        int m = lane + 64 * r;
        float4 p = XP[m];
        float dot = __fadd_rn(__fadd_rn(__fmul_rn(a0, p.x), __fmul_rn(a1, p.y)),
                              __fmul_rn(a2, p.z));
        float d2 = __fsub_rn(__fadd_rn(sqa, p.w), __fmul_rn(2.0f, dot));
        d2 = fmaxf(d2, 0.0f);
        key[r] = (__float_as_uint(d2) & 0xFFFFF800u) | (unsigned)m;  // < 2^31
    }
    unsigned prev1 = 0;  // prev extracted key + 1 (0 on first iteration)
#pragma unroll
    for (int it = 0; it < KNB; it++) {
        unsigned best = 0xFFFFFFFFu;
#pragma unroll
        for (int r = 0; r < 32; r++)
            best = min(best, key[r] - prev1);  // removed/smaller keys wrap huge
#pragma unroll
        for (int st = 1; st < 64; st <<= 1) {
            unsigned ob = __shfl_xor((int)best, st, 64);
            best = min(best, ob);
        }
        unsigned abskey = best + prev1;
        int m = (int)(abskey & 2047u);
        if (lane == 0) nbl[w][it] = m;
        prev1 = abskey + 1u;
    }
    __builtin_amdgcn_wave_barrier();
    if (lane < KNB) {
        int ia = nbl[w][lane];
        const float* ct = corrTgt + ((size_t)b * NN + ia) * 3;
        ptb[w][lane][0] = ct[0];
        ptb[w][lane][1] = ct[1];
        ptb[w][lane][2] = ct[2];
    }
    __builtin_amdgcn_wave_barrier();
    const float* ctn = corrTgt + ((size_t)b * NN + n) * 3;
    float t0 = ctn[0], t1 = ctn[1], t2 = ctn[2];
    if (lane < NPAIR) {
        int k = lane, ja = 0, cnt = 9;
        while (k >= cnt) { k -= cnt; ja++; cnt--; }
        int jb = ja + 1 + k;
        int ia = nbl[w][ja], ib = nbl[w][jb];
        float4 pa = XP[ia], pb = XP[ib];
        float area_s = tri_area(a0, a1, a2, pa.x, pa.y, pa.z, pb.x, pb.y, pb.z);
        float area_t = tri_area(t0, t1, t2, ptb[w][ja][0], ptb[w][ja][1], ptb[w][ja][2],
                                ptb[w][jb][0], ptb[w][jb][1], ptb[w][jb][2]);
        const float EPSF = 1e-6f;
        float ee = __fmul_rn(EPSF, EPSF);
        float lt2 = __fadd_rn(area_t, EPSF);
        float da = __fsub_rn(area_s, lt2);
        float sa = __fadd_rn(area_s, lt2);
        float num = __fadd_rn(__fadd_rn(ee, ee), __fmul_rn(da, da));
        float den = __fadd_rn(__fadd_rn(ee, ee), __fmul_rn(sa, sa));
        la[w][lane] = __fdiv_rn(num, den);
        rg[w][lane] = sqrtf(num);
    }
    __builtin_amdgcn_wave_barrier();
    if (lane < NPAIR) {
        float x = la[w][lane];
        int rk = 0;
        for (int j = 0; j < NPAIR; j++) {
            float y = la[w][j];
            rk += (y < x || (y == x && j < lane)) ? 1 : 0;
        }
        srt[w][rk] = x;
    }
    __builtin_amdgcn_wave_barrier();
    float l2v = 0.f;
    if (lane < NPAIR) l2v = __fadd_rn(srt[w][lane], __fmul_rn(0.1f, rg[w][lane]));
    __builtin_amdgcn_wave_barrier();
    if (lane < NPAIR) la[w][lane] = l2v;
    __builtin_amdgcn_wave_barrier();
    if (lane < NPAIR) {
        float x = la[w][lane];
        int rk = 0;
        for (int j = 0; j < NPAIR; j++) {
            float y = la[w][j];
            rk += (y < x || (y == x && j < lane)) ? 1 : 0;
        }
        srt[w][rk] = x;
    }
    __builtin_amdgcn_wave_barrier();
    float med = srt[w][22];
    float thr = __fmul_rn(3.0f, med);
    float term = 0.f;
    if (lane < KNB) {
        float vv = la[w][lane];
        if (vv > thr) vv = 0.f;
        term = sqrtf(__fadd_rn(vv, 1e-6f));
    }
#pragma unroll
    for (int st = 1; st < 64; st <<= 1) term += __shfl_xor(term, st, 64);
    if (lane == 0) pointLoss[b * NN + n] = __fdiv_rn(term, 10.0f);
}

// ---------------------------------------------------------------------------
// K4: fused finish — 1024 threads/batch: refined corres, min, weight,
// Procrustes reductions, 3x3 Jacobi SVD
// ---------------------------------------------------------------------------
__device__ double det3(const double M[3][3]) {
    return M[0][0] * (M[1][1] * M[2][2] - M[1][2] * M[2][1]) -
           M[0][1] * (M[1][0] * M[2][2] - M[1][2] * M[2][0]) +
           M[0][2] * (M[1][0] * M[2][1] - M[1][1] * M[2][0]);
}

__global__ __launch_bounds__(1024) void fused_finish(const float* __restrict__ pointLoss,
                                                     const int* __restrict__ flags,
                                                     const unsigned long long* __restrict__ keys,
                                                     const int* __restrict__ corresIn,
                                                     const float* __restrict__ srcP,
                                                     const float* __restrict__ tgtP,
                                                     float* __restrict__ outR,
                                                     float* __restrict__ outT,
                                                     float* __restrict__ outC,
                                                     float* __restrict__ outW) {
    int b = blockIdx.x, tid = threadIdx.x;
    int w = tid >> 6, lane = tid & 63;
    __shared__ int csh[NN];
    __shared__ float wsh[NN];
    __shared__ float fred[1024];
    __shared__ double sd[16][9];
    __shared__ double sxySh[9];

    // phase 1: final corres (apply refined keys) + min(pointLoss)
    float mn = 3.4e38f;
    for (int n = tid; n < NN; n += 1024) {
        int row = b * NN + n;
        int ci = corresIn[row];
        if (flags[row]) ci = (int)(~(unsigned)(keys[row] & 0xFFFFFFFFull));
        csh[n] = ci;
        outC[row] = (float)ci;
        mn = fminf(mn, pointLoss[row]);
    }
    fred[tid] = mn;
    __syncthreads();
    for (int st = 512; st > 0; st >>= 1) {
        if (tid < st) fred[tid] = fminf(fred[tid], fred[tid + st]);
        __syncthreads();
    }
    float minL = fred[0];
    __syncthreads();

    // phase 2: weight
    for (int n = tid; n < NN; n += 1024) {
        int row = b * NN + n;
        float l = __fsub_rn(pointLoss[row], minL);
        float z = __fmul_rn(-20.0f, l);
        float ez = expf(z);
        float sg = __fdiv_rn(ez, __fadd_rn(1.0f, ez));
        float wf = (__fmul_rn(2.0f, sg) > 0.5f) ? 1.0f : 0.0f;
        wsh[n] = wf;
        outW[row] = wf;
    }
    __syncthreads();

    // phase 3: Procrustes reductions (double, 16 waves)
    const float* xs = srcP + (size_t)b * 3 * NN;
    const float* ts = tgtP + (size_t)b * 3 * NN;
    double acc7[7] = {0, 0, 0, 0, 0, 0, 0};
    for (int n = tid; n < NN; n += 1024) {
        if (wsh[n] != 0.0f) {
            acc7[0] += 1.0;
            acc7[1] += (double)xs[n];
            acc7[2] += (double)xs[NN + n];
            acc7[3] += (double)xs[2 * NN + n];
            int m = csh[n];
            acc7[4] += (double)ts[m];
            acc7[5] += (double)ts[NN + m];
            acc7[6] += (double)ts[2 * NN + m];
        }
    }
#pragma unroll
    for (int q = 0; q < 7; q++) {
        double r = wave_red_sum_d(acc7[q]);
        if (lane == 0) sd[w][q] = r;
    }
    __syncthreads();
    double tot7[7];
#pragma unroll
    for (int q = 0; q < 7; q++) {
        double s2 = 0;
#pragma unroll
        for (int w2 = 0; w2 < 16; w2++) s2 += sd[w2][q];
        tot7[q] = s2;
    }
    __syncthreads();

    double W1e = tot7[0] + 1e-7;
    double mux0 = tot7[1] / W1e, mux1 = tot7[2] / W1e, mux2 = tot7[3] / W1e;
    double muy0 = tot7[4] / W1e, muy1 = tot7[5] / W1e, muy2 = tot7[6] / W1e;

    double s[9] = {0, 0, 0, 0, 0, 0, 0, 0, 0};
    for (int n = tid; n < NN; n += 1024) {
        if (wsh[n] != 0.0f) {
            double dx0 = (double)xs[n] - mux0;
            double dx1 = (double)xs[NN + n] - mux1;
            double dx2 = (double)xs[2 * NN + n] - mux2;
            int m = csh[n];
            double dy0 = (double)ts[m] - muy0;
            double dy1 = (double)ts[NN + m] - muy1;
            double dy2 = (double)ts[2 * NN + m] - muy2;
            s[0] += dy0 * dx0; s[1] += dy0 * dx1; s[2] += dy0 * dx2;
            s[3] += dy1 * dx0; s[4] += dy1 * dx1; s[5] += dy1 * dx2;
            s[6] += dy2 * dx0; s[7] += dy2 * dx1; s[8] += dy2 * dx2;
        }
    }
#pragma unroll
    for (int q = 0; q < 9; q++) {
        double r = wave_red_sum_d(s[q]);
        if (lane == 0) sd[w][q] = r;
    }
    __syncthreads();
    if (tid < 9) {
        double s2 = 0;
#pragma unroll
        for (int w2 = 0; w2 < 16; w2++) s2 += sd[w2][tid];
        sxySh[tid] = s2 / W1e;
    }
    __syncthreads();

    // phase 4: one thread does the 3x3 Jacobi SVD -> R, T
    if (tid == 0) {
        double Bm2[3][3], V[3][3];
        for (int r = 0; r < 3; r++)
            for (int c2 = 0; c2 < 3; c2++) {
                Bm2[r][c2] = sxySh[r * 3 + c2];
                V[r][c2] = (r == c2) ? 1.0 : 0.0;
            }
        double nrm2 = 0;
        for (int r = 0; r < 3; r++)
            for (int c2 = 0; c2 < 3; c2++) nrm2 += Bm2[r][c2] * Bm2[r][c2];

        for (int sweep = 0; sweep < 60; sweep++) {
            double off = 0;
            for (int p = 0; p < 2; p++) {
                for (int q = p + 1; q < 3; q++) {
                    double al = 0, be = 0, ga = 0;
                    for (int i = 0; i < 3; i++) {
                        al += Bm2[i][p] * Bm2[i][p];
                        be += Bm2[i][q] * Bm2[i][q];
                        ga += Bm2[i][p] * Bm2[i][q];
                    }
                    off += ga * ga;
                    if (fabs(ga) > 1e-300) {
                        double ze = (be - al) / (2.0 * ga);
                        double tt = copysign(1.0, ze) / (fabs(ze) + sqrt(1.0 + ze * ze));
                        double c = 1.0 / sqrt(1.0 + tt * tt), sn = c * tt;
                        for (int i = 0; i < 3; i++) {
                            double bp = Bm2[i][p], bq = Bm2[i][q];
                            Bm2[i][p] = c * bp - sn * bq;
                            Bm2[i][q] = sn * bp + c * bq;
                            double vp = V[i][p], vq = V[i][q];
                            V[i][p] = c * vp - sn * vq;
                            V[i][q] = sn * vp + c * vq;
                        }
                    }
                }
            }
            if (off <= 1e-30 * nrm2 * nrm2) break;
        }
        double sig[3];
        for (int j = 0; j < 3; j++) {
            double ss = 0;
            for (int i = 0; i < 3; i++) ss += Bm2[i][j] * Bm2[i][j];
            sig[j] = sqrt(ss);
        }
        for (int a = 0; a < 2; a++)
            for (int j = 0; j < 2 - a; j++)
                if (sig[j] < sig[j + 1]) {
                    double t2 = sig[j]; sig[j] = sig[j + 1]; sig[j + 1] = t2;
                    for (int i = 0; i < 3; i++) {
                        double tb = Bm2[i][j]; Bm2[i][j] = Bm2[i][j + 1]; Bm2[i][j + 1] = tb;
                        double tv = V[i][j]; V[i][j] = V[i][j + 1]; V[i][j + 1] = tv;
                    }
                }
        double U[3][3];
        for (int j = 0; j < 3; j++) {
            double inv = (sig[j] > 1e-150) ? 1.0 / sig[j] : 0.0;
            for (int i = 0; i < 3; i++) U[i][j] = Bm2[i][j] * inv;
        }
        if (sig[2] <= 1e-10 * (sig[0] + 1e-300)) {
            double u0 = U[1][0] * U[2][1] - U[2][0] * U[1][1];
            double u1 = U[2][0] * U[0][1] - U[0][0] * U[2][1];
            double u2 = U[0][0] * U[1][1] - U[1][0] * U[0][1];
            double nr = sqrt(u0 * u0 + u1 * u1 + u2 * u2);
            if (nr > 1e-150) { U[0][2] = u0 / nr; U[1][2] = u1 / nr; U[2][2] = u2 / nr; }
        }
        double dU = det3(U), dV = det3(V);
        double s3 = (dU * dV >= 0.0) ? 1.0 : -1.0;
        double R[3][3];
        for (int i = 0; i < 3; i++)
            for (int j = 0; j < 3; j++)
                R[i][j] = U[i][0] * V[j][0] + U[i][1] * V[j][1] + s3 * U[i][2] * V[j][2];
        double mux[3] = {mux0, mux1, mux2};
        double muy[3] = {muy0, muy1, muy2};
        for (int i = 0; i < 3; i++) {
            for (int j = 0; j < 3; j++) outR[b * 9 + i * 3 + j] = (float)R[i][j];
            double t2 = muy[i] - (R[i][0] * mux[0] + R[i][1] * mux[1] + R[i][2] * mux[2]);
            outT[b * 3 + i] = (float)t2;
        }
    }
}

// ---------------------------------------------------------------------------
// host launcher
// ---------------------------------------------------------------------------
extern "C" void kernel_launch(void* const* d_in, const int* in_sizes, int n_in,
                              void* d_out, int out_size, void* d_ws, size_t ws_size,
                              hipStream_t stream) {
    const float* srcE = (const float*)d_in[0];
    const float* tgtE = (const float*)d_in[1];
    const float* srcP = (const float*)d_in[2];
    const float* tgtP = (const float*)d_in[3];
    float* out = (float*)d_out;  // R[36] T[12] corres[8192] weight[8192]

    char* w = (char*)d_ws;
    size_t off = 0;
    auto alloc = [&](size_t bytes) -> void* {
        void* p = w + off;
        off = (off + bytes + 255) & ~(size_t)255;
        return p;
    };
    float* corrTgt = (float*)alloc((size_t)NBATCH * NN * 3 * 4);
    int* corres = (int*)alloc((size_t)NBATCH * NN * 4);
    int* flags = (int*)alloc((size_t)NBATCH * NN * 4);
    unsigned long long* keys = (unsigned long long*)alloc((size_t)NBATCH * NN * 8);
    int* list = (int*)alloc((size_t)NBATCH * NN * 32 * 4);  // worst-case all tiles
    int* count = (int*)alloc(256);
    float* pointLoss = (float*)alloc((size_t)NBATCH * NN * 4);
    size_t planeShorts = (size_t)NBATCH * 16 * NN * 32;  // 8.4 MB per plane
    short* Ah = (short*)alloc(planeShorts * 2);
    short* Bh = (short*)alloc(planeShorts * 2);
    float* part = (float*)alloc((size_t)NBATCH * NN * 32 * 4 * 4);  // 4.2 MB

    prep_planes<<<dim3(512, NBATCH, 2), 256, 0, stream>>>(srcE, tgtE, Ah, Bh, count);
    gemm_fused<<<dim3(NN / 128, NN / 128, NBATCH), 256, 0, stream>>>(Ah, Bh, part);
    combine_rows<<<dim3(NN / 4, NBATCH), 256, 0, stream>>>(part, tgtP, corres, flags, list,
                                                           count, keys, corrTgt);
    gfm_kernel<<<dim3(NN / 8, NBATCH), 512, 0, stream>>>(srcP, corrTgt, pointLoss);
    refine_tiles<<<dim3(2048), 256, 0, stream>>>(srcE, tgtE, list, count, keys);
    fused_finish<<<NBATCH, 1024, 0, stream>>>(pointLoss, flags, keys, corres, srcP, tgtP,
                                              out, out + 36, out + 48, out + 48 + NBATCH * NN);
}